// Round 13
// baseline (265.509 us; speedup 1.0000x reference)
//
#include <hip/hip_runtime.h>
#include <math.h>

typedef __attribute__((ext_vector_type(4))) float f32x4;
typedef __attribute__((ext_vector_type(8))) short s16x8;
typedef __attribute__((ext_vector_type(4))) short s16x4;

__device__ __forceinline__ unsigned short f2b(float f) {
    union { float f; unsigned u; } v; v.f = f;
    unsigned r = v.u + 0x7fffu + ((v.u >> 16) & 1u);
    return (unsigned short)(r >> 16);
}
__device__ __forceinline__ float b2f(unsigned short u) {
    union { unsigned u; float f; } v; v.u = ((unsigned)u) << 16;
    return v.f;
}

// global -> LDS direct copy, 16 B per lane. LDS dest = wave-uniform base + lane*16.
__device__ __forceinline__ void gll16(const void* g, void* l) {
    __builtin_amdgcn_global_load_lds((const __attribute__((address_space(1))) unsigned int*)g,
                                     (__attribute__((address_space(3))) unsigned int*)l,
                                     16, 0, 0);
}

constexpr int kF = 512;
constexpr int kW = 256;
constexpr int kFW = kF * kW;   // 131072

// ================= prep: LayerNorm (bid<32, w-coalesced) + src transpose ======
__global__ __launch_bounds__(256) void prep_kernel(const float* __restrict__ x,
                                                   const float* __restrict__ g,
                                                   const float* __restrict__ b,
                                                   unsigned short* __restrict__ hTb,
                                                   const float* __restrict__ src,
                                                   unsigned short* __restrict__ SRCT) {
    __shared__ float tile[64][65];
    __shared__ float s1[4][64], s2[4][64];
    int bid = blockIdx.x;
    int t = threadIdx.x;
    if (bid < 32) {
        int c = bid >> 2;
        int w0 = (bid & 3) * 64;
        int wi = t & 63, fg = t >> 6;          // fg 0..3, f-range fg*128..+127
        const float* xb = x + (size_t)c * kFW + w0 + wi;
        float sum = 0.f, sum2 = 0.f;
        for (int j = 0; j < 128; ++j) {
            float v = xb[(size_t)(fg * 128 + j) * kW];
            sum += v; sum2 += v * v;
        }
        s1[fg][wi] = sum; s2[fg][wi] = sum2;
        __syncthreads();
        float ts = s1[0][wi] + s1[1][wi] + s1[2][wi] + s1[3][wi];
        float tq = s2[0][wi] + s2[1][wi] + s2[2][wi] + s2[3][wi];
        float mu = ts * (1.0f / 512.0f);
        float rstd = rsqrtf(tq * (1.0f / 512.0f) - mu * mu + 1e-5f);
        const float* gc = g + c * kF + fg * 128;
        const float* bc = b + c * kF + fg * 128;
        unsigned short* ob = hTb + (size_t)c * kFW + (size_t)(w0 + wi) * kF + fg * 128;
        for (int j = 0; j < 128; j += 4) {
            float v0 = xb[(size_t)(fg * 128 + j + 0) * kW];
            float v1 = xb[(size_t)(fg * 128 + j + 1) * kW];
            float v2 = xb[(size_t)(fg * 128 + j + 2) * kW];
            float v3 = xb[(size_t)(fg * 128 + j + 3) * kW];
            s16x4 p = { (short)f2b((v0 - mu) * rstd * gc[j + 0] + bc[j + 0]),
                        (short)f2b((v1 - mu) * rstd * gc[j + 1] + bc[j + 1]),
                        (short)f2b((v2 - mu) * rstd * gc[j + 2] + bc[j + 2]),
                        (short)f2b((v3 - mu) * rstd * gc[j + 3] + bc[j + 3]) };
            *(s16x4*)(&ob[j]) = p;
        }
    } else {
        int fid = bid - 32;
        int c = fid >> 5;
        int f0 = ((fid >> 2) & 7) * 64, w0 = (fid & 3) * 64;
        int tw = t & 63, tf4 = t >> 6;
        for (int i = 0; i < 16; ++i) {
            int f = tf4 * 16 + i;
            tile[f][tw] = src[(size_t)c * kFW + (size_t)(f0 + f) * kW + w0 + tw];
        }
        __syncthreads();
        int w = t >> 2, fc = (t & 3) * 16;
        unsigned short* ob = SRCT + (size_t)c * kFW + (size_t)(w0 + w) * kF + f0 + fc;
        for (int j = 0; j < 16; j += 4) {
            s16x4 p = { (short)f2b(tile[fc + j + 0][w]), (short)f2b(tile[fc + j + 1][w]),
                        (short)f2b(tile[fc + j + 2][w]), (short)f2b(tile[fc + j + 3][w]) };
            *(s16x4*)(&ob[j]) = p;
        }
    }
}

// ================= weight-streaming GEMM, single-buffer gll (round-8 skeleton) =
// omode: 0 = f32 [m][n] (+kz*c_split), 1 = bf16 [m][n], 2 = bf16 T [n][m]
struct WSeg { const float* A; const unsigned short* B; void* C; int omode; };
struct WB8 { WSeg s[8]; };

template<int BN>
__global__ __launch_bounds__(256) void wgemmT(WB8 wb, int M, int K, int Klocal,
                                              long a_ch, long b_ch, long c_ch, long c_split,
                                              int segshift, int nm, int ntiles, int ksplit) {
    constexpr int NF = BN / 16;
    constexpr int RPW = BN / 4;
    constexpr int GP = BN / 32;
    __shared__ unsigned short lds[BN * 64];

    int t = threadIdx.x, lane = t & 63, wv = t >> 6;
    int l16 = lane & 15, l4 = lane >> 4;

    int id = blockIdx.x;
    int r = id & 7, j = id >> 3;
    int per = nm * ntiles * ksplit;
    int y = r + 8 * (j / per);
    int rem = j % per;
    int mt = rem % nm;
    int rem2 = rem / nm;
    int ntile = rem2 % ntiles;
    int kz = rem2 / ntiles;
    int seg = y >> segshift, c = y & ((1 << segshift) - 1);
    WSeg sg = wb.s[seg];
    int bm = mt * 64;
    int bn = ntile * BN;
    int kbase = kz * Klocal;

    const float* A = sg.A + (size_t)c * a_ch + kbase;
    const unsigned short* Bc = sg.B + (size_t)c * b_ch + kbase;
    const float* arow = A + (size_t)(bm + wv * 16 + l16) * K + l4 * 8;

    int rsub = lane >> 3;
    int gsw = ((lane & 7) ^ rsub) * 8;
    const unsigned short* bsrc = Bc + (size_t)(bn + wv * RPW + rsub) * K + gsw;

    f32x4 acc[NF];
    #pragma unroll
    for (int i = 0; i < NF; ++i) acc[i] = (f32x4){0.f, 0.f, 0.f, 0.f};

    f32x4 pa0 = __builtin_nontemporal_load((const f32x4*)arow);
    f32x4 pa1 = __builtin_nontemporal_load((const f32x4*)(arow + 4));

    for (int kc = 0; kc < Klocal; kc += 64) {
        if (kc) __syncthreads();
        #pragma unroll
        for (int i = 0; i < GP; ++i) {
            int r0 = wv * RPW + i * 8;
            gll16(bsrc + (size_t)(i * 8) * K + kc, (char*)lds + (r0 << 7));
        }
        __syncthreads();
        #pragma unroll
        for (int ks = 0; ks < 2; ++ks) {
            f32x4 c0 = pa0, c1 = pa1;
            int nk = kc + (ks + 1) * 32;
            if (nk < Klocal) {
                pa0 = __builtin_nontemporal_load((const f32x4*)(arow + nk));
                pa1 = __builtin_nontemporal_load((const f32x4*)(arow + nk + 4));
            }
            s16x8 af = { (short)f2b(c0.x), (short)f2b(c0.y), (short)f2b(c0.z), (short)f2b(c0.w),
                         (short)f2b(c1.x), (short)f2b(c1.y), (short)f2b(c1.z), (short)f2b(c1.w) };
            #pragma unroll
            for (int ni = 0; ni < NF; ++ni) {
                int rr = ni * 16 + l16;
                s16x8 bf = *(const s16x8*)(&lds[rr * 64 + ((ks * 32 + l4 * 8) ^ ((rr & 7) << 3))]);
                acc[ni] = __builtin_amdgcn_mfma_f32_16x16x32_bf16(af, bf, acc[ni], 0, 0, 0);
            }
        }
    }

    int m0 = bm + wv * 16 + l4 * 4;
    if (sg.omode == 2) {
        unsigned short* C = (unsigned short*)sg.C + (size_t)c * c_ch;
        #pragma unroll
        for (int ni = 0; ni < NF; ++ni) {
            int n = bn + ni * 16 + l16;
            s16x4 pk = { (short)f2b(acc[ni][0]), (short)f2b(acc[ni][1]),
                         (short)f2b(acc[ni][2]), (short)f2b(acc[ni][3]) };
            *(s16x4*)(&C[(size_t)n * M + m0]) = pk;
        }
    } else if (sg.omode == 1) {
        unsigned short* C = (unsigned short*)sg.C + (size_t)c * c_ch;
        #pragma unroll
        for (int ni = 0; ni < NF; ++ni) {
            int n = bn + ni * 16 + l16;
            #pragma unroll
            for (int rr = 0; rr < 4; ++rr)
                C[(size_t)(m0 + rr) * 256 + n] = f2b(acc[ni][rr]);
        }
    } else {
        float* C = (float*)sg.C + (size_t)c * c_ch + (size_t)kz * c_split;
        #pragma unroll
        for (int ni = 0; ni < NF; ++ni) {
            int n = bn + ni * 16 + l16;
            #pragma unroll
            for (int rr = 0; rr < 4; ++rr)
                C[(size_t)(m0 + rr) * 256 + n] = acc[ni][rr];
        }
    }
}

// ================= big-GEMM variant: 128m x 256n, 512 thr, dbuf issue-ahead ===
__global__ __launch_bounds__(512) void wgemm512(WB8 wb, int M, int K, int Klocal,
                                                long a_ch, long b_ch, long c_ch, long c_split,
                                                int segshift, int nm, int ksplit) {
    __shared__ unsigned short lds[2][16384];
    int t = threadIdx.x, lane = t & 63, wv = t >> 6;
    int l16 = lane & 15, l4 = lane >> 4;

    int id = blockIdx.x;
    int r = id & 7, j = id >> 3;
    int per = nm * ksplit;
    int y = r + 8 * (j / per);
    int rem = j % per;
    int mt = rem % nm;
    int kz = rem / nm;
    int seg = y >> segshift, c = y & ((1 << segshift) - 1);
    WSeg sg = wb.s[seg];
    int bm = mt * 128;
    int kbase = kz * Klocal;

    const float* A = sg.A + (size_t)c * a_ch + kbase;
    const unsigned short* Bc = sg.B + (size_t)c * b_ch + kbase;
    const float* arow = A + (size_t)(bm + wv * 16 + l16) * K + l4 * 8;

    int rsub = lane >> 3;
    int gsw = ((lane & 7) ^ rsub) * 8;
    const unsigned short* bsrc = Bc + (size_t)(wv * 32 + rsub) * K + gsw;

    f32x4 acc[16];
    #pragma unroll
    for (int i = 0; i < 16; ++i) acc[i] = (f32x4){0.f, 0.f, 0.f, 0.f};

    #pragma unroll
    for (int i = 0; i < 4; ++i)
        gll16(bsrc + (size_t)(i * 8) * K, (char*)lds[0] + ((wv * 32 + i * 8) << 7));

    f32x4 pa0 = __builtin_nontemporal_load((const f32x4*)arow);
    f32x4 pa1 = __builtin_nontemporal_load((const f32x4*)(arow + 4));

    int nc = Klocal >> 6;
    for (int cc = 0; cc < nc; ++cc) {
        __syncthreads();
        if (cc + 1 < nc) {
            int kc = (cc + 1) * 64;
            #pragma unroll
            for (int i = 0; i < 4; ++i)
                gll16(bsrc + (size_t)(i * 8) * K + kc,
                      (char*)lds[(cc + 1) & 1] + ((wv * 32 + i * 8) << 7));
        }
        const unsigned short* buf = lds[cc & 1];
        #pragma unroll
        for (int ks = 0; ks < 2; ++ks) {
            f32x4 c0 = pa0, c1 = pa1;
            int nk = cc * 64 + (ks + 1) * 32;
            if (nk < Klocal) {
                pa0 = __builtin_nontemporal_load((const f32x4*)(arow + nk));
                pa1 = __builtin_nontemporal_load((const f32x4*)(arow + nk + 4));
            }
            s16x8 af = { (short)f2b(c0.x), (short)f2b(c0.y), (short)f2b(c0.z), (short)f2b(c0.w),
                         (short)f2b(c1.x), (short)f2b(c1.y), (short)f2b(c1.z), (short)f2b(c1.w) };
            #pragma unroll
            for (int ni = 0; ni < 16; ++ni) {
                int rr = ni * 16 + l16;
                s16x8 bf = *(const s16x8*)(&buf[rr * 64 + ((ks * 32 + l4 * 8) ^ ((rr & 7) << 3))]);
                acc[ni] = __builtin_amdgcn_mfma_f32_16x16x32_bf16(af, bf, acc[ni], 0, 0, 0);
            }
        }
    }

    int m0 = bm + wv * 16 + l4 * 4;
    if (sg.omode == 2) {
        unsigned short* C = (unsigned short*)sg.C + (size_t)c * c_ch;
        #pragma unroll
        for (int ni = 0; ni < 16; ++ni) {
            int n = ni * 16 + l16;
            s16x4 pk = { (short)f2b(acc[ni][0]), (short)f2b(acc[ni][1]),
                         (short)f2b(acc[ni][2]), (short)f2b(acc[ni][3]) };
            *(s16x4*)(&C[(size_t)n * M + m0]) = pk;
        }
    } else if (sg.omode == 1) {
        unsigned short* C = (unsigned short*)sg.C + (size_t)c * c_ch;
        #pragma unroll
        for (int ni = 0; ni < 16; ++ni) {
            int n = ni * 16 + l16;
            #pragma unroll
            for (int rr = 0; rr < 4; ++rr)
                C[(size_t)(m0 + rr) * 256 + n] = f2b(acc[ni][rr]);
        }
    } else {
        float* C = (float*)sg.C + (size_t)c * c_ch + (size_t)kz * c_split;
        #pragma unroll
        for (int ni = 0; ni < 16; ++ni) {
            int n = ni * 16 + l16;
            #pragma unroll
            for (int rr = 0; rr < 4; ++rr)
                C[(size_t)(m0 + rr) * 256 + n] = acc[ni][rr];
        }
    }
}

// ================= fused attention: QK^T + softmax + PV =======================
__global__ __launch_bounds__(256) void attn_kernel(
    const unsigned short* __restrict__ Qt, const unsigned short* __restrict__ Kt,
    const unsigned short* __restrict__ VN, float* __restrict__ S,
    unsigned short* __restrict__ ATTT, float scale)
{
    __shared__ unsigned short q_lds[4096];
    __shared__ unsigned short kv_lds[16384];
    __shared__ unsigned short p_lds[16384];
    __shared__ float smax[4][64], ssum[4][64], sinv[64];
    int t = threadIdx.x, lane = t & 63, wv = t >> 6;
    int l16 = lane & 15, l4 = lane >> 4;
    int ch = blockIdx.y, c = ch >> 3, h = ch & 7;
    int bm = blockIdx.x * 64;
    const unsigned short* Qb = Qt + (size_t)c * kFW + h * 64;
    const unsigned short* Kb = Kt + (size_t)c * kFW + h * 64;
    const unsigned short* Vb = VN + (size_t)c * kFW + (size_t)(h * 64) * 256;
    float* Sb = S + (size_t)ch * 65536;
    unsigned short* Ab = ATTT + (size_t)c * kFW + h * 64;

    s16x8 qr[2], kr[8], vr[8];
    #pragma unroll
    for (int i = 0; i < 2; ++i) {
        int idx = i * 256 + t; int rr = idx >> 3, ck = idx & 7;
        qr[i] = *(const s16x8*)(Qb + (size_t)(bm + rr) * 512 + ck * 8);
    }
    #pragma unroll
    for (int i = 0; i < 8; ++i) {
        int idx = i * 256 + t; int rr = idx >> 3, ck = idx & 7;
        kr[i] = *(const s16x8*)(Kb + (size_t)rr * 512 + ck * 8);
    }
    #pragma unroll
    for (int i = 0; i < 8; ++i) {
        int idx = i * 256 + t; int d = idx >> 5, cs = idx & 31;
        vr[i] = *(const s16x8*)(Vb + (size_t)d * 256 + cs * 8);
    }
    #pragma unroll
    for (int i = 0; i < 2; ++i) {
        int idx = i * 256 + t; int rr = idx >> 3, ck = idx & 7;
        *(s16x8*)(&q_lds[rr * 64 + ((ck * 8) ^ ((rr & 7) << 3))]) = qr[i];
    }
    #pragma unroll
    for (int i = 0; i < 8; ++i) {
        int idx = i * 256 + t; int rr = idx >> 3, ck = idx & 7;
        *(s16x8*)(&kv_lds[rr * 64 + ((ck * 8) ^ ((rr & 7) << 3))]) = kr[i];
    }
    __syncthreads();

    f32x4 acc[4][4];
    #pragma unroll
    for (int i = 0; i < 4; ++i)
        #pragma unroll
        for (int jj = 0; jj < 4; ++jj) acc[i][jj] = (f32x4){0.f, 0.f, 0.f, 0.f};
    #pragma unroll
    for (int ks = 0; ks < 2; ++ks) {
        s16x8 af[4], bfr[4];
        #pragma unroll
        for (int mi = 0; mi < 4; ++mi) {
            int rq = mi * 16 + l16;
            af[mi] = *(const s16x8*)(&q_lds[rq * 64 + ((ks * 32 + l4 * 8) ^ ((rq & 7) << 3))]);
        }
        #pragma unroll
        for (int ni = 0; ni < 4; ++ni) {
            int rk = wv * 64 + ni * 16 + l16;
            bfr[ni] = *(const s16x8*)(&kv_lds[rk * 64 + ((ks * 32 + l4 * 8) ^ ((rk & 7) << 3))]);
        }
        #pragma unroll
        for (int mi = 0; mi < 4; ++mi)
            #pragma unroll
            for (int ni = 0; ni < 4; ++ni)
                acc[mi][ni] = __builtin_amdgcn_mfma_f32_16x16x32_bf16(af[mi], bfr[ni], acc[mi][ni], 0, 0, 0);
    }

    #pragma unroll
    for (int mi = 0; mi < 4; ++mi)
        #pragma unroll
        for (int ni = 0; ni < 4; ++ni) {
            acc[mi][ni] *= scale;
            int col = wv * 64 + ni * 16 + l16;
            int row0 = bm + mi * 16 + l4 * 4;
            #pragma unroll
            for (int rr = 0; rr < 4; ++rr)
                Sb[(size_t)(row0 + rr) * 256 + col] = acc[mi][ni][rr];
        }

    float rmax[4][4];
    #pragma unroll
    for (int mi = 0; mi < 4; ++mi)
        #pragma unroll
        for (int rr = 0; rr < 4; ++rr)
            rmax[mi][rr] = fmaxf(fmaxf(acc[mi][0][rr], acc[mi][1][rr]), fmaxf(acc[mi][2][rr], acc[mi][3][rr]));
    #pragma unroll
    for (int d = 1; d < 16; d <<= 1)
        #pragma unroll
        for (int mi = 0; mi < 4; ++mi)
            #pragma unroll
            for (int rr = 0; rr < 4; ++rr)
                rmax[mi][rr] = fmaxf(rmax[mi][rr], __shfl_xor(rmax[mi][rr], d));
    if (l16 == 0)
        #pragma unroll
        for (int mi = 0; mi < 4; ++mi)
            #pragma unroll
            for (int rr = 0; rr < 4; ++rr)
                smax[wv][mi * 16 + l4 * 4 + rr] = rmax[mi][rr];
    __syncthreads();
    float rsum[4][4];
    #pragma unroll
    for (int mi = 0; mi < 4; ++mi)
        #pragma unroll
        for (int rr = 0; rr < 4; ++rr) {
            int row = mi * 16 + l4 * 4 + rr;
            float rM = fmaxf(fmaxf(smax[0][row], smax[1][row]), fmaxf(smax[2][row], smax[3][row]));
            rsum[mi][rr] = 0.f;
            #pragma unroll
            for (int ni = 0; ni < 4; ++ni) {
                float e = __expf(acc[mi][ni][rr] - rM);
                acc[mi][ni][rr] = e;
                rsum[mi][rr] += e;
            }
        }
    #pragma unroll
    for (int d = 1; d < 16; d <<= 1)
        #pragma unroll
        for (int mi = 0; mi < 4; ++mi)
            #pragma unroll
            for (int rr = 0; rr < 4; ++rr)
                rsum[mi][rr] += __shfl_xor(rsum[mi][rr], d);
    if (l16 == 0)
        #pragma unroll
        for (int mi = 0; mi < 4; ++mi)
            #pragma unroll
            for (int rr = 0; rr < 4; ++rr)
                ssum[wv][mi * 16 + l4 * 4 + rr] = rsum[mi][rr];
    __syncthreads();

    #pragma unroll
    for (int i = 0; i < 8; ++i) {
        int idx = i * 256 + t; int d = idx >> 5, cs = idx & 31;
        *(s16x8*)(&kv_lds[d * 256 + ((cs * 8) ^ ((d & 7) << 3))]) = vr[i];
    }
    #pragma unroll
    for (int mi = 0; mi < 4; ++mi)
        #pragma unroll
        for (int ni = 0; ni < 4; ++ni) {
            int col = wv * 64 + ni * 16 + l16;
            int cb = col & ~7, cl = col & 7;
            #pragma unroll
            for (int rr = 0; rr < 4; ++rr) {
                int row = mi * 16 + l4 * 4 + rr;
                p_lds[row * 256 + (cb ^ ((row & 7) << 3)) + cl] = f2b(acc[mi][ni][rr]);
            }
        }
    if (t < 64) sinv[t] = 1.f / (ssum[0][t] + ssum[1][t] + ssum[2][t] + ssum[3][t]);
    __syncthreads();

    f32x4 po[4];
    #pragma unroll
    for (int ni = 0; ni < 4; ++ni) po[ni] = (f32x4){0.f, 0.f, 0.f, 0.f};
    int qrow = wv * 16 + l16;
    #pragma unroll
    for (int ks = 0; ks < 8; ++ks) {
        s16x8 paf = *(const s16x8*)(&p_lds[qrow * 256 + ((ks * 32 + l4 * 8) ^ ((qrow & 7) << 3))]);
        #pragma unroll
        for (int ni = 0; ni < 4; ++ni) {
            int rd = ni * 16 + l16;
            s16x8 bf = *(const s16x8*)(&kv_lds[rd * 256 + ((ks * 32 + l4 * 8) ^ ((rd & 7) << 3))]);
            po[ni] = __builtin_amdgcn_mfma_f32_16x16x32_bf16(paf, bf, po[ni], 0, 0, 0);
        }
    }
    #pragma unroll
    for (int ni = 0; ni < 4; ++ni) {
        int d = ni * 16 + l16;
        #pragma unroll
        for (int rr = 0; rr < 4; ++rr) {
            int row = wv * 16 + l4 * 4 + rr;
            Ab[(size_t)(bm + row) * 512 + d] = f2b(po[ni][rr] * sinv[row]);
        }
    }
}

// ================= batched conv (1,3) + 8->8 mix, 5 groups — VECTORIZED x8 =====
struct ConvArgs {
    const unsigned short* in[5];
    unsigned short* out[5];
    const float* cw[5];
    const float* cb[5];
    int mode[5];
};

__global__ __launch_bounds__(256) void conv5_kernel(ConvArgs a) {
    int g = blockIdx.y;
    __shared__ float scw[192]; __shared__ float scb[8];
    int t = threadIdx.x;
    if (t < 192) scw[t] = a.cw[g][t];
    if (t >= 192 && t < 200) scb[t - 192] = a.cb[g][t - 192];
    __syncthreads();
    const unsigned short* in = a.in[g];
    unsigned short* out = a.out[g];
    size_t gi = ((size_t)blockIdx.x * 256 + t) * 8;
    int mode = a.mode[g];
    float acc[8][8];
    #pragma unroll
    for (int o = 0; o < 8; ++o)
        #pragma unroll
        for (int jj = 0; jj < 8; ++jj) acc[o][jj] = scb[o];

    if (mode == 0) {
        int w = (int)(gi >> 9);
        bool hm = w > 0, hp = w < 255;
        #pragma unroll
        for (int i = 0; i < 8; ++i) {
            size_t base = (size_t)i * kFW + gi;
            s16x8 vc = *(const s16x8*)(&in[base]);
            s16x8 vm = hm ? *(const s16x8*)(&in[base - 512]) : (s16x8){0,0,0,0,0,0,0,0};
            s16x8 vp = hp ? *(const s16x8*)(&in[base + 512]) : (s16x8){0,0,0,0,0,0,0,0};
            float fm[8], fc[8], fp[8];
            #pragma unroll
            for (int jj = 0; jj < 8; ++jj) {
                fm[jj] = b2f((unsigned short)vm[jj]);
                fc[jj] = b2f((unsigned short)vc[jj]);
                fp[jj] = b2f((unsigned short)vp[jj]);
            }
            #pragma unroll
            for (int o = 0; o < 8; ++o) {
                const float* wp = &scw[(o * 8 + i) * 3];
                #pragma unroll
                for (int jj = 0; jj < 8; ++jj)
                    acc[o][jj] += wp[0] * fm[jj] + wp[1] * fc[jj] + wp[2] * fp[jj];
            }
        }
    } else {
        int w0 = (int)(gi & 255);
        #pragma unroll
        for (int i = 0; i < 8; ++i) {
            size_t base = (size_t)i * kFW + gi;
            s16x8 vc = *(const s16x8*)(&in[base]);
            float em = (w0 > 0) ? b2f(in[base - 1]) : 0.f;
            float ep = (w0 + 8 < 256) ? b2f(in[base + 8]) : 0.f;
            float fc[8];
            #pragma unroll
            for (int jj = 0; jj < 8; ++jj) fc[jj] = b2f((unsigned short)vc[jj]);
            float fm[8], fp[8];
            fm[0] = em;
            #pragma unroll
            for (int jj = 1; jj < 8; ++jj) fm[jj] = fc[jj - 1];
            #pragma unroll
            for (int jj = 0; jj < 7; ++jj) fp[jj] = fc[jj + 1];
            fp[7] = ep;
            #pragma unroll
            for (int o = 0; o < 8; ++o) {
                const float* wp = &scw[(o * 8 + i) * 3];
                #pragma unroll
                for (int jj = 0; jj < 8; ++jj)
                    acc[o][jj] += wp[0] * fm[jj] + wp[1] * fc[jj] + wp[2] * fp[jj];
            }
        }
    }
    #pragma unroll
    for (int o = 0; o < 8; ++o) {
        s16x8 pk;
        #pragma unroll
        for (int jj = 0; jj < 8; ++jj) pk[jj] = (short)f2b(acc[o][jj]);
        *(s16x8*)(&out[(size_t)o * kFW + gi]) = pk;
    }
}

// ================= fused 16->8 mix + conv (CA query path), T layout ===========
__global__ __launch_bounds__(256) void mixconv_kernel(const unsigned short* __restrict__ in,
                                                      const float* __restrict__ dw,
                                                      const float* __restrict__ cw,
                                                      const float* __restrict__ cb,
                                                      unsigned short* __restrict__ out) {
    __shared__ float sdw[128], scw[192], scb[8];
    int t = threadIdx.x;
    if (t < 128) sdw[t] = dw[t];
    if (t >= 128 && t < 136) scb[t - 128] = cb[t - 128];
    if (t < 192) scw[t] = cw[t];
    __syncthreads();
    int gi = blockIdx.x * 256 + t;
    int w = gi >> 9;
    bool hm = w > 0, hp = w < 255;
    float xc[16], xm[16], xp[16];
    #pragma unroll
    for (int cc = 0; cc < 16; ++cc) {
        size_t base = (size_t)cc * kFW + gi;
        xc[cc] = b2f(in[base]);
        xm[cc] = hm ? b2f(in[base - 512]) : 0.f;
        xp[cc] = hp ? b2f(in[base + 512]) : 0.f;
    }
    float mm[8], m0[8], mp[8];
    #pragma unroll
    for (int o = 0; o < 8; ++o) {
        float am = 0.f, a0 = 0.f, ap = 0.f;
        #pragma unroll
        for (int cc = 0; cc < 16; ++cc) {
            float wv = sdw[o * 16 + cc];
            am += wv * xm[cc]; a0 += wv * xc[cc]; ap += wv * xp[cc];
        }
        mm[o] = am; m0[o] = a0; mp[o] = ap;
    }
    #pragma unroll
    for (int o = 0; o < 8; ++o) {
        float acc = scb[o];
        #pragma unroll
        for (int i = 0; i < 8; ++i) {
            const float* wp = &scw[(o * 8 + i) * 3];
            acc += wp[0] * mm[i] + wp[1] * m0[i] + wp[2] * mp[i];
        }
        out[(size_t)o * kFW + gi] = f2b(acc);
    }
}

// ================= FFN1: 24->24 mix + exact GELU, in place — VECTORIZED x4 ====
__global__ __launch_bounds__(256) void gelu24_kernel(unsigned short* __restrict__ z,
                                                     const float* __restrict__ dw) {
    __shared__ float sdw[576];
    int t = threadIdx.x;
    for (int i = t; i < 576; i += 256) sdw[i] = dw[i];
    __syncthreads();
    size_t gi = ((size_t)blockIdx.x * 256 + t) * 4;
    const size_t CH = (size_t)256 * 2048;
    float xv[24][4];
    #pragma unroll
    for (int cc = 0; cc < 24; ++cc) {
        s16x4 v = *(const s16x4*)(&z[cc * CH + gi]);
        #pragma unroll
        for (int jj = 0; jj < 4; ++jj) xv[cc][jj] = b2f((unsigned short)v[jj]);
    }
    #pragma unroll
    for (int o = 0; o < 24; ++o) {
        float s0 = 0.f, s1 = 0.f, s2 = 0.f, s3 = 0.f;
        #pragma unroll
        for (int cc = 0; cc < 24; ++cc) {
            float wv = sdw[o * 24 + cc];
            s0 += wv * xv[cc][0]; s1 += wv * xv[cc][1];
            s2 += wv * xv[cc][2]; s3 += wv * xv[cc][3];
        }
        s0 = 0.5f * s0 * (1.0f + erff(s0 * 0.7071067811865475f));
        s1 = 0.5f * s1 * (1.0f + erff(s1 * 0.7071067811865475f));
        s2 = 0.5f * s2 * (1.0f + erff(s2 * 0.7071067811865475f));
        s3 = 0.5f * s3 * (1.0f + erff(s3 * 0.7071067811865475f));
        s16x4 pk = { (short)f2b(s0), (short)f2b(s1), (short)f2b(s2), (short)f2b(s3) };
        *(s16x4*)(&z[o * CH + gi]) = pk;
    }
}

// ================= FFN2 reduce(4 partials) + 24->8 mix + residual =============
__global__ __launch_bounds__(256) void final_mix_add4(const float* __restrict__ x,
                                                      const float* __restrict__ z2,
                                                      const float* __restrict__ dw,
                                                      float* __restrict__ out) {
    __shared__ float sdw[192];
    int t = threadIdx.x;
    if (t < 192) sdw[t] = dw[t];
    __syncthreads();
    int gi = blockIdx.x * 256 + t;
    const size_t PSZ = (size_t)24 * kFW;
    float xv[24];
    #pragma unroll
    for (int cc = 0; cc < 24; ++cc) {
        size_t o = (size_t)cc * kFW + gi;
        xv[cc] = (z2[o] + z2[PSZ + o]) + (z2[2 * PSZ + o] + z2[3 * PSZ + o]);
    }
    #pragma unroll
    for (int o = 0; o < 8; ++o) {
        float s = 0.f;
        #pragma unroll
        for (int cc = 0; cc < 24; ++cc) s += sdw[o * 24 + cc] * xv[cc];
        out[(size_t)o * kFW + gi] = x[(size_t)o * kFW + gi] + s;
    }
}

// ================= launch =====================================================
extern "C" void kernel_launch(void* const* d_in, const int* in_sizes, int n_in,
                              void* d_out, int out_size, void* d_ws, size_t ws_size,
                              hipStream_t stream) {
    const float* x       = (const float*)d_in[0];
    const float* src     = (const float*)d_in[1];
    const float* ln_g    = (const float*)d_in[2];
    const float* ln_b    = (const float*)d_in[3];
    const float* sa_q_pw = (const float*)d_in[4];
    const float* sa_q_cw = (const float*)d_in[5];
    const float* sa_q_cb = (const float*)d_in[6];
    const float* sa_k_pw = (const float*)d_in[7];
    const float* sa_k_cw = (const float*)d_in[8];
    const float* sa_k_cb = (const float*)d_in[9];
    const float* sa_v_pw = (const float*)d_in[10];
    const float* sa_v_cw = (const float*)d_in[11];
    const float* sa_v_cb = (const float*)d_in[12];
    const float* sa_o_pw = (const float*)d_in[13];
    const float* ca_q_pw = (const float*)d_in[14];
    const float* ca_q_dw = (const float*)d_in[15];
    const float* ca_q_cw = (const float*)d_in[16];
    const float* ca_q_cb = (const float*)d_in[17];
    const float* ca_k_pw = (const float*)d_in[18];
    const float* ca_k_cw = (const float*)d_in[19];
    const float* ca_k_cb = (const float*)d_in[20];
    const float* ca_v_pw = (const float*)d_in[21];
    const float* ca_v_cw = (const float*)d_in[22];
    const float* ca_v_cb = (const float*)d_in[23];
    const float* ca_o_pw = (const float*)d_in[24];
    const float* ffn1_pw = (const float*)d_in[25];
    const float* ffn1_dw = (const float*)d_in[26];
    const float* ffn2_pw = (const float*)d_in[27];
    const float* ffn2_dw = (const float*)d_in[28];

    float* out  = (float*)d_out;
    float* qk1o = out + 1048576;
    float* qk2o = out + 1048576 + 4194304;

    unsigned char* ws = (unsigned char*)d_ws;
    unsigned short* CAT24  = (unsigned short*)(ws + 0);
    unsigned short* hTb    = CAT24;
    unsigned short* saTb   = CAT24 + 8 * (size_t)kFW;
    unsigned short* caTb   = CAT24 + 16 * (size_t)kFW;
    unsigned short* SRCT   = (unsigned short*)(ws + 6291456);
    unsigned short* preQ   = (unsigned short*)(ws + 8388608);
    unsigned short* preK   = (unsigned short*)(ws + 10485760);
    unsigned short* preVsa = (unsigned short*)(ws + 12582912);
    unsigned short* preKca = (unsigned short*)(ws + 14680064);
    unsigned short* preVca = (unsigned short*)(ws + 16777216);
    unsigned short* QT     = (unsigned short*)(ws + 18874368);
    unsigned short* KT     = (unsigned short*)(ws + 20971520);
    unsigned short* VNsa   = (unsigned short*)(ws + 23068672);
    unsigned short* KTca   = (unsigned short*)(ws + 25165824);
    unsigned short* VNca   = (unsigned short*)(ws + 27262976);
    unsigned short* PRE16  = (unsigned short*)(ws + 29360128);
    unsigned short* QTca   = (unsigned short*)(ws + 33554432);
    unsigned short* ATTT   = (unsigned short*)(ws + 35651584);
    // FFN phase (attention scratch dead by then):
    unsigned short* Z0T    = (unsigned short*)(ws + 8388608);   // 25 MB [24][256][2048]
    float*          Z2P    = (float*)(ws + 37748736);           // 4 x 12.6 MB partials

    const float qscale = 0.044194173824159216f;   // 1/sqrt(512)
    dim3 blk(256);
    dim3 blk512(512);

    prep_kernel<<<288, blk, 0, stream>>>(x, ln_g, ln_b, hTb, src, SRCT);

    // ---- batched projections: SA q,k,v + CA k,v + CA q (h half) ----
    WB8 p6;
    p6.s[0] = { sa_q_pw, hTb,  preQ,   2 };
    p6.s[1] = { sa_k_pw, hTb,  preK,   2 };
    p6.s[2] = { sa_v_pw, hTb,  preVsa, 1 };
    p6.s[3] = { ca_k_pw, SRCT, preKca, 2 };
    p6.s[4] = { ca_v_pw, SRCT, preVca, 1 };
    p6.s[5] = { ca_q_pw, hTb,  PRE16,  2 };
    p6.s[6] = p6.s[0]; p6.s[7] = p6.s[0];
    wgemmT<256><<<dim3(384), blk, 0, stream>>>(p6, 512, 512, 512, 262144, kFW, kFW, 0, 3, 8, 1, 1);

    ConvArgs c5;
    c5.in[0] = preQ;   c5.out[0] = QT;   c5.cw[0] = sa_q_cw; c5.cb[0] = sa_q_cb; c5.mode[0] = 0;
    c5.in[1] = preK;   c5.out[1] = KT;   c5.cw[1] = sa_k_cw; c5.cb[1] = sa_k_cb; c5.mode[1] = 0;
    c5.in[2] = preVsa; c5.out[2] = VNsa; c5.cw[2] = sa_v_cw; c5.cb[2] = sa_v_cb; c5.mode[2] = 1;
    c5.in[3] = preKca; c5.out[3] = KTca; c5.cw[3] = ca_k_cw; c5.cb[3] = ca_k_cb; c5.mode[3] = 0;
    c5.in[4] = preVca; c5.out[4] = VNca; c5.cw[4] = ca_v_cw; c5.cb[4] = ca_v_cb; c5.mode[4] = 1;
    conv5_kernel<<<dim3(64, 5), blk, 0, stream>>>(c5);

    // ---- self attention (fused QK+softmax+PV) ----
    attn_kernel<<<dim3(4, 64), blk, 0, stream>>>(QT, KT, VNsa, qk1o, ATTT, qscale);
    WB8 so;
    so.s[0] = { sa_o_pw, ATTT, saTb, 2 };
    for (int i = 1; i < 8; ++i) so.s[i] = so.s[0];
    wgemmT<64><<<dim3(256), blk, 0, stream>>>(so, 512, 512, 512, 262144, kFW, kFW, 0, 8, 8, 4, 1);

    // ---- cross attention ----
    WB8 cq2;
    cq2.s[0] = { ca_q_pw + 8 * 262144, saTb, PRE16 + 8 * (size_t)kFW, 2 };
    for (int i = 1; i < 8; ++i) cq2.s[i] = cq2.s[0];
    wgemmT<64><<<dim3(256), blk, 0, stream>>>(cq2, 512, 512, 512, 262144, kFW, kFW, 0, 8, 8, 4, 1);
    mixconv_kernel<<<512, blk, 0, stream>>>(PRE16, ca_q_dw, ca_q_cw, ca_q_cb, QTca);

    attn_kernel<<<dim3(4, 64), blk, 0, stream>>>(QTca, KTca, VNca, qk2o, ATTT, qscale);
    WB8 co;
    co.s[0] = { ca_o_pw, ATTT, caTb, 2 };
    for (int i = 1; i < 8; ++i) co.s[i] = co.s[0];
    wgemmT<64><<<dim3(256), blk, 0, stream>>>(co, 512, 512, 512, 262144, kFW, kFW, 0, 8, 8, 4, 1);

    // ---- FFN ----
    WB8 f1;
    f1.s[0] = { ffn1_pw, CAT24, Z0T, 2 };
    for (int i = 1; i < 8; ++i) f1.s[i] = f1.s[0];
    wgemm512<<<dim3(384), blk512, 0, stream>>>(f1, 2048, 512, 512, 1048576, kFW, 524288, 0, 8, 16, 1);
    gelu24_kernel<<<512, blk, 0, stream>>>(Z0T, ffn1_dw);
    WB8 f2;
    f2.s[0] = { ffn2_pw, Z0T, Z2P, 0 };
    for (int i = 1; i < 8; ++i) f2.s[i] = f2.s[0];
    wgemm512<<<dim3(384), blk512, 0, stream>>>(f2, 512, 2048, 512, 1048576, 524288, kFW, 3145728, 8, 4, 4);
    final_mix_add4<<<512, blk, 0, stream>>>(x, Z2P, ffn2_dw, out);
}

// Round 14
// 262.825 us; speedup vs baseline: 1.0102x; 1.0102x over previous
//
#include <hip/hip_runtime.h>
#include <math.h>

typedef __attribute__((ext_vector_type(4))) float f32x4;
typedef __attribute__((ext_vector_type(8))) short s16x8;
typedef __attribute__((ext_vector_type(4))) short s16x4;

__device__ __forceinline__ unsigned short f2b(float f) {
    union { float f; unsigned u; } v; v.f = f;
    unsigned r = v.u + 0x7fffu + ((v.u >> 16) & 1u);
    return (unsigned short)(r >> 16);
}
__device__ __forceinline__ float b2f(unsigned short u) {
    union { unsigned u; float f; } v; v.u = ((unsigned)u) << 16;
    return v.f;
}

// global -> LDS direct copy, 16 B per lane. LDS dest = wave-uniform base + lane*16.
__device__ __forceinline__ void gll16(const void* g, void* l) {
    __builtin_amdgcn_global_load_lds((const __attribute__((address_space(1))) unsigned int*)g,
                                     (__attribute__((address_space(3))) unsigned int*)l,
                                     16, 0, 0);
}

constexpr int kF = 512;
constexpr int kW = 256;
constexpr int kFW = kF * kW;   // 131072

// ================= prep: LayerNorm (bid<128) + src transpose (bid>=128) ========
__global__ __launch_bounds__(256) void prep_kernel(const float* __restrict__ x,
                                                   const float* __restrict__ g,
                                                   const float* __restrict__ b,
                                                   unsigned short* __restrict__ hTb,
                                                   const float* __restrict__ src,
                                                   unsigned short* __restrict__ SRCT) {
    __shared__ float tile[64][65];
    __shared__ float s1[16][16], s2[16][16];
    int bid = blockIdx.x;
    int t = threadIdx.x;
    if (bid < 128) {
        int c = bid >> 4;
        int w0 = (bid & 15) * 16;
        int wi = t & 15, fg = t >> 4;
        const float* xb = x + (size_t)c * kFW + w0 + wi;
        float sum = 0.f, sum2 = 0.f;
        for (int j = 0; j < 32; ++j) {
            float v = xb[(size_t)(fg * 32 + j) * kW];
            sum += v; sum2 += v * v;
        }
        s1[fg][wi] = sum; s2[fg][wi] = sum2;
        __syncthreads();
        float ts = 0.f, tq = 0.f;
        #pragma unroll
        for (int j = 0; j < 16; ++j) { ts += s1[j][wi]; tq += s2[j][wi]; }
        float mu = ts * (1.0f / 512.0f);
        float rstd = rsqrtf(tq * (1.0f / 512.0f) - mu * mu + 1e-5f);
        const float* gc = g + c * kF + fg * 32;
        const float* bc = b + c * kF + fg * 32;
        unsigned short* ob = hTb + (size_t)c * kFW + (size_t)(w0 + wi) * kF + fg * 32;
        for (int j = 0; j < 32; j += 4) {
            float v0 = xb[(size_t)(fg * 32 + j + 0) * kW];
            float v1 = xb[(size_t)(fg * 32 + j + 1) * kW];
            float v2 = xb[(size_t)(fg * 32 + j + 2) * kW];
            float v3 = xb[(size_t)(fg * 32 + j + 3) * kW];
            s16x4 p = { (short)f2b((v0 - mu) * rstd * gc[j + 0] + bc[j + 0]),
                        (short)f2b((v1 - mu) * rstd * gc[j + 1] + bc[j + 1]),
                        (short)f2b((v2 - mu) * rstd * gc[j + 2] + bc[j + 2]),
                        (short)f2b((v3 - mu) * rstd * gc[j + 3] + bc[j + 3]) };
            *(s16x4*)(&ob[j]) = p;
        }
    } else {
        int fid = bid - 128;
        int c = fid >> 5;
        int f0 = ((fid >> 2) & 7) * 64, w0 = (fid & 3) * 64;
        int tw = t & 63, tf4 = t >> 6;
        for (int i = 0; i < 16; ++i) {
            int f = tf4 * 16 + i;
            tile[f][tw] = src[(size_t)c * kFW + (size_t)(f0 + f) * kW + w0 + tw];
        }
        __syncthreads();
        int w = t >> 2, fc = (t & 3) * 16;
        unsigned short* ob = SRCT + (size_t)c * kFW + (size_t)(w0 + w) * kF + f0 + fc;
        for (int j = 0; j < 16; j += 4) {
            s16x4 p = { (short)f2b(tile[fc + j + 0][w]), (short)f2b(tile[fc + j + 1][w]),
                        (short)f2b(tile[fc + j + 2][w]), (short)f2b(tile[fc + j + 3][w]) };
            *(s16x4*)(&ob[j]) = p;
        }
    }
}

// ================= weight-streaming GEMM, single-buffer gll (round-8 skeleton) =
// omode: 0 = f32 [m][n] (+kz*c_split), 1 = bf16 [m][n], 2 = bf16 T [n][m]
struct WSeg { const float* A; const unsigned short* B; void* C; int omode; };
struct WB8 { WSeg s[8]; };

template<int BN>
__global__ __launch_bounds__(256) void wgemmT(WB8 wb, int M, int K, int Klocal,
                                              long a_ch, long b_ch, long c_ch, long c_split,
                                              int segshift, int nm, int ntiles, int ksplit) {
    constexpr int NF = BN / 16;
    constexpr int RPW = BN / 4;
    constexpr int GP = BN / 32;
    __shared__ unsigned short lds[BN * 64];

    int t = threadIdx.x, lane = t & 63, wv = t >> 6;
    int l16 = lane & 15, l4 = lane >> 4;

    int id = blockIdx.x;
    int r = id & 7, j = id >> 3;
    int per = nm * ntiles * ksplit;
    int y = r + 8 * (j / per);
    int rem = j % per;
    int mt = rem % nm;
    int rem2 = rem / nm;
    int ntile = rem2 % ntiles;
    int kz = rem2 / ntiles;
    int seg = y >> segshift, c = y & ((1 << segshift) - 1);
    WSeg sg = wb.s[seg];
    int bm = mt * 64;
    int bn = ntile * BN;
    int kbase = kz * Klocal;

    const float* A = sg.A + (size_t)c * a_ch + kbase;
    const unsigned short* Bc = sg.B + (size_t)c * b_ch + kbase;
    const float* arow = A + (size_t)(bm + wv * 16 + l16) * K + l4 * 8;

    int rsub = lane >> 3;
    int gsw = ((lane & 7) ^ rsub) * 8;
    const unsigned short* bsrc = Bc + (size_t)(bn + wv * RPW + rsub) * K + gsw;

    f32x4 acc[NF];
    #pragma unroll
    for (int i = 0; i < NF; ++i) acc[i] = (f32x4){0.f, 0.f, 0.f, 0.f};

    f32x4 pa0 = __builtin_nontemporal_load((const f32x4*)arow);
    f32x4 pa1 = __builtin_nontemporal_load((const f32x4*)(arow + 4));

    for (int kc = 0; kc < Klocal; kc += 64) {
        if (kc) __syncthreads();
        #pragma unroll
        for (int i = 0; i < GP; ++i) {
            int r0 = wv * RPW + i * 8;
            gll16(bsrc + (size_t)(i * 8) * K + kc, (char*)lds + (r0 << 7));
        }
        __syncthreads();
        #pragma unroll
        for (int ks = 0; ks < 2; ++ks) {
            f32x4 c0 = pa0, c1 = pa1;
            int nk = kc + (ks + 1) * 32;
            if (nk < Klocal) {
                pa0 = __builtin_nontemporal_load((const f32x4*)(arow + nk));
                pa1 = __builtin_nontemporal_load((const f32x4*)(arow + nk + 4));
            }
            s16x8 af = { (short)f2b(c0.x), (short)f2b(c0.y), (short)f2b(c0.z), (short)f2b(c0.w),
                         (short)f2b(c1.x), (short)f2b(c1.y), (short)f2b(c1.z), (short)f2b(c1.w) };
            #pragma unroll
            for (int ni = 0; ni < NF; ++ni) {
                int rr = ni * 16 + l16;
                s16x8 bf = *(const s16x8*)(&lds[rr * 64 + ((ks * 32 + l4 * 8) ^ ((rr & 7) << 3))]);
                acc[ni] = __builtin_amdgcn_mfma_f32_16x16x32_bf16(af, bf, acc[ni], 0, 0, 0);
            }
        }
    }

    int m0 = bm + wv * 16 + l4 * 4;
    if (sg.omode == 2) {
        unsigned short* C = (unsigned short*)sg.C + (size_t)c * c_ch;
        #pragma unroll
        for (int ni = 0; ni < NF; ++ni) {
            int n = bn + ni * 16 + l16;
            s16x4 pk = { (short)f2b(acc[ni][0]), (short)f2b(acc[ni][1]),
                         (short)f2b(acc[ni][2]), (short)f2b(acc[ni][3]) };
            *(s16x4*)(&C[(size_t)n * M + m0]) = pk;
        }
    } else if (sg.omode == 1) {
        unsigned short* C = (unsigned short*)sg.C + (size_t)c * c_ch;
        #pragma unroll
        for (int ni = 0; ni < NF; ++ni) {
            int n = bn + ni * 16 + l16;
            #pragma unroll
            for (int rr = 0; rr < 4; ++rr)
                C[(size_t)(m0 + rr) * 256 + n] = f2b(acc[ni][rr]);
        }
    } else {
        float* C = (float*)sg.C + (size_t)c * c_ch + (size_t)kz * c_split;
        #pragma unroll
        for (int ni = 0; ni < NF; ++ni) {
            int n = bn + ni * 16 + l16;
            #pragma unroll
            for (int rr = 0; rr < 4; ++rr)
                C[(size_t)(m0 + rr) * 256 + n] = acc[ni][rr];
        }
    }
}

// ================= big-GEMM variant: 128m x 256n, 512 thr, dbuf issue-ahead ===
__global__ __launch_bounds__(512) void wgemm512(WB8 wb, int M, int K, int Klocal,
                                                long a_ch, long b_ch, long c_ch, long c_split,
                                                int segshift, int nm, int ksplit) {
    __shared__ unsigned short lds[2][16384];
    int t = threadIdx.x, lane = t & 63, wv = t >> 6;
    int l16 = lane & 15, l4 = lane >> 4;

    int id = blockIdx.x;
    int r = id & 7, j = id >> 3;
    int per = nm * ksplit;
    int y = r + 8 * (j / per);
    int rem = j % per;
    int mt = rem % nm;
    int kz = rem / nm;
    int seg = y >> segshift, c = y & ((1 << segshift) - 1);
    WSeg sg = wb.s[seg];
    int bm = mt * 128;
    int kbase = kz * Klocal;

    const float* A = sg.A + (size_t)c * a_ch + kbase;
    const unsigned short* Bc = sg.B + (size_t)c * b_ch + kbase;
    const float* arow = A + (size_t)(bm + wv * 16 + l16) * K + l4 * 8;

    int rsub = lane >> 3;
    int gsw = ((lane & 7) ^ rsub) * 8;
    const unsigned short* bsrc = Bc + (size_t)(wv * 32 + rsub) * K + gsw;

    f32x4 acc[16];
    #pragma unroll
    for (int i = 0; i < 16; ++i) acc[i] = (f32x4){0.f, 0.f, 0.f, 0.f};

    #pragma unroll
    for (int i = 0; i < 4; ++i)
        gll16(bsrc + (size_t)(i * 8) * K, (char*)lds[0] + ((wv * 32 + i * 8) << 7));

    f32x4 pa0 = __builtin_nontemporal_load((const f32x4*)arow);
    f32x4 pa1 = __builtin_nontemporal_load((const f32x4*)(arow + 4));

    int nc = Klocal >> 6;
    for (int cc = 0; cc < nc; ++cc) {
        __syncthreads();
        if (cc + 1 < nc) {
            int kc = (cc + 1) * 64;
            #pragma unroll
            for (int i = 0; i < 4; ++i)
                gll16(bsrc + (size_t)(i * 8) * K + kc,
                      (char*)lds[(cc + 1) & 1] + ((wv * 32 + i * 8) << 7));
        }
        const unsigned short* buf = lds[cc & 1];
        #pragma unroll
        for (int ks = 0; ks < 2; ++ks) {
            f32x4 c0 = pa0, c1 = pa1;
            int nk = cc * 64 + (ks + 1) * 32;
            if (nk < Klocal) {
                pa0 = __builtin_nontemporal_load((const f32x4*)(arow + nk));
                pa1 = __builtin_nontemporal_load((const f32x4*)(arow + nk + 4));
            }
            s16x8 af = { (short)f2b(c0.x), (short)f2b(c0.y), (short)f2b(c0.z), (short)f2b(c0.w),
                         (short)f2b(c1.x), (short)f2b(c1.y), (short)f2b(c1.z), (short)f2b(c1.w) };
            #pragma unroll
            for (int ni = 0; ni < 16; ++ni) {
                int rr = ni * 16 + l16;
                s16x8 bf = *(const s16x8*)(&buf[rr * 64 + ((ks * 32 + l4 * 8) ^ ((rr & 7) << 3))]);
                acc[ni] = __builtin_amdgcn_mfma_f32_16x16x32_bf16(af, bf, acc[ni], 0, 0, 0);
            }
        }
    }

    int m0 = bm + wv * 16 + l4 * 4;
    if (sg.omode == 2) {
        unsigned short* C = (unsigned short*)sg.C + (size_t)c * c_ch;
        #pragma unroll
        for (int ni = 0; ni < 16; ++ni) {
            int n = ni * 16 + l16;
            s16x4 pk = { (short)f2b(acc[ni][0]), (short)f2b(acc[ni][1]),
                         (short)f2b(acc[ni][2]), (short)f2b(acc[ni][3]) };
            *(s16x4*)(&C[(size_t)n * M + m0]) = pk;
        }
    } else if (sg.omode == 1) {
        unsigned short* C = (unsigned short*)sg.C + (size_t)c * c_ch;
        #pragma unroll
        for (int ni = 0; ni < 16; ++ni) {
            int n = ni * 16 + l16;
            #pragma unroll
            for (int rr = 0; rr < 4; ++rr)
                C[(size_t)(m0 + rr) * 256 + n] = f2b(acc[ni][rr]);
        }
    } else {
        float* C = (float*)sg.C + (size_t)c * c_ch + (size_t)kz * c_split;
        #pragma unroll
        for (int ni = 0; ni < 16; ++ni) {
            int n = ni * 16 + l16;
            #pragma unroll
            for (int rr = 0; rr < 4; ++rr)
                C[(size_t)(m0 + rr) * 256 + n] = acc[ni][rr];
        }
    }
}

// ================= fused attention: QK^T + softmax + PV =======================
__global__ __launch_bounds__(256) void attn_kernel(
    const unsigned short* __restrict__ Qt, const unsigned short* __restrict__ Kt,
    const unsigned short* __restrict__ VN, float* __restrict__ S,
    unsigned short* __restrict__ ATTT, float scale)
{
    __shared__ unsigned short q_lds[4096];
    __shared__ unsigned short kv_lds[16384];
    __shared__ unsigned short p_lds[16384];
    __shared__ float smax[4][64], ssum[4][64], sinv[64];
    int t = threadIdx.x, lane = t & 63, wv = t >> 6;
    int l16 = lane & 15, l4 = lane >> 4;
    int ch = blockIdx.y, c = ch >> 3, h = ch & 7;
    int bm = blockIdx.x * 64;
    const unsigned short* Qb = Qt + (size_t)c * kFW + h * 64;
    const unsigned short* Kb = Kt + (size_t)c * kFW + h * 64;
    const unsigned short* Vb = VN + (size_t)c * kFW + (size_t)(h * 64) * 256;
    float* Sb = S + (size_t)ch * 65536;
    unsigned short* Ab = ATTT + (size_t)c * kFW + h * 64;

    s16x8 qr[2], kr[8], vr[8];
    #pragma unroll
    for (int i = 0; i < 2; ++i) {
        int idx = i * 256 + t; int rr = idx >> 3, ck = idx & 7;
        qr[i] = *(const s16x8*)(Qb + (size_t)(bm + rr) * 512 + ck * 8);
    }
    #pragma unroll
    for (int i = 0; i < 8; ++i) {
        int idx = i * 256 + t; int rr = idx >> 3, ck = idx & 7;
        kr[i] = *(const s16x8*)(Kb + (size_t)rr * 512 + ck * 8);
    }
    #pragma unroll
    for (int i = 0; i < 8; ++i) {
        int idx = i * 256 + t; int d = idx >> 5, cs = idx & 31;
        vr[i] = *(const s16x8*)(Vb + (size_t)d * 256 + cs * 8);
    }
    #pragma unroll
    for (int i = 0; i < 2; ++i) {
        int idx = i * 256 + t; int rr = idx >> 3, ck = idx & 7;
        *(s16x8*)(&q_lds[rr * 64 + ((ck * 8) ^ ((rr & 7) << 3))]) = qr[i];
    }
    #pragma unroll
    for (int i = 0; i < 8; ++i) {
        int idx = i * 256 + t; int rr = idx >> 3, ck = idx & 7;
        *(s16x8*)(&kv_lds[rr * 64 + ((ck * 8) ^ ((rr & 7) << 3))]) = kr[i];
    }
    __syncthreads();

    f32x4 acc[4][4];
    #pragma unroll
    for (int i = 0; i < 4; ++i)
        #pragma unroll
        for (int jj = 0; jj < 4; ++jj) acc[i][jj] = (f32x4){0.f, 0.f, 0.f, 0.f};
    #pragma unroll
    for (int ks = 0; ks < 2; ++ks) {
        s16x8 af[4], bfr[4];
        #pragma unroll
        for (int mi = 0; mi < 4; ++mi) {
            int rq = mi * 16 + l16;
            af[mi] = *(const s16x8*)(&q_lds[rq * 64 + ((ks * 32 + l4 * 8) ^ ((rq & 7) << 3))]);
        }
        #pragma unroll
        for (int ni = 0; ni < 4; ++ni) {
            int rk = wv * 64 + ni * 16 + l16;
            bfr[ni] = *(const s16x8*)(&kv_lds[rk * 64 + ((ks * 32 + l4 * 8) ^ ((rk & 7) << 3))]);
        }
        #pragma unroll
        for (int mi = 0; mi < 4; ++mi)
            #pragma unroll
            for (int ni = 0; ni < 4; ++ni)
                acc[mi][ni] = __builtin_amdgcn_mfma_f32_16x16x32_bf16(af[mi], bfr[ni], acc[mi][ni], 0, 0, 0);
    }

    #pragma unroll
    for (int mi = 0; mi < 4; ++mi)
        #pragma unroll
        for (int ni = 0; ni < 4; ++ni) {
            acc[mi][ni] *= scale;
            int col = wv * 64 + ni * 16 + l16;
            int row0 = bm + mi * 16 + l4 * 4;
            #pragma unroll
            for (int rr = 0; rr < 4; ++rr)
                Sb[(size_t)(row0 + rr) * 256 + col] = acc[mi][ni][rr];
        }

    float rmax[4][4];
    #pragma unroll
    for (int mi = 0; mi < 4; ++mi)
        #pragma unroll
        for (int rr = 0; rr < 4; ++rr)
            rmax[mi][rr] = fmaxf(fmaxf(acc[mi][0][rr], acc[mi][1][rr]), fmaxf(acc[mi][2][rr], acc[mi][3][rr]));
    #pragma unroll
    for (int d = 1; d < 16; d <<= 1)
        #pragma unroll
        for (int mi = 0; mi < 4; ++mi)
            #pragma unroll
            for (int rr = 0; rr < 4; ++rr)
                rmax[mi][rr] = fmaxf(rmax[mi][rr], __shfl_xor(rmax[mi][rr], d));
    if (l16 == 0)
        #pragma unroll
        for (int mi = 0; mi < 4; ++mi)
            #pragma unroll
            for (int rr = 0; rr < 4; ++rr)
                smax[wv][mi * 16 + l4 * 4 + rr] = rmax[mi][rr];
    __syncthreads();
    float rsum[4][4];
    #pragma unroll
    for (int mi = 0; mi < 4; ++mi)
        #pragma unroll
        for (int rr = 0; rr < 4; ++rr) {
            int row = mi * 16 + l4 * 4 + rr;
            float rM = fmaxf(fmaxf(smax[0][row], smax[1][row]), fmaxf(smax[2][row], smax[3][row]));
            rsum[mi][rr] = 0.f;
            #pragma unroll
            for (int ni = 0; ni < 4; ++ni) {
                float e = __expf(acc[mi][ni][rr] - rM);
                acc[mi][ni][rr] = e;
                rsum[mi][rr] += e;
            }
        }
    #pragma unroll
    for (int d = 1; d < 16; d <<= 1)
        #pragma unroll
        for (int mi = 0; mi < 4; ++mi)
            #pragma unroll
            for (int rr = 0; rr < 4; ++rr)
                rsum[mi][rr] += __shfl_xor(rsum[mi][rr], d);
    if (l16 == 0)
        #pragma unroll
        for (int mi = 0; mi < 4; ++mi)
            #pragma unroll
            for (int rr = 0; rr < 4; ++rr)
                ssum[wv][mi * 16 + l4 * 4 + rr] = rsum[mi][rr];
    __syncthreads();

    #pragma unroll
    for (int i = 0; i < 8; ++i) {
        int idx = i * 256 + t; int d = idx >> 5, cs = idx & 31;
        *(s16x8*)(&kv_lds[d * 256 + ((cs * 8) ^ ((d & 7) << 3))]) = vr[i];
    }
    #pragma unroll
    for (int mi = 0; mi < 4; ++mi)
        #pragma unroll
        for (int ni = 0; ni < 4; ++ni) {
            int col = wv * 64 + ni * 16 + l16;
            int cb = col & ~7, cl = col & 7;
            #pragma unroll
            for (int rr = 0; rr < 4; ++rr) {
                int row = mi * 16 + l4 * 4 + rr;
                p_lds[row * 256 + (cb ^ ((row & 7) << 3)) + cl] = f2b(acc[mi][ni][rr]);
            }
        }
    if (t < 64) sinv[t] = 1.f / (ssum[0][t] + ssum[1][t] + ssum[2][t] + ssum[3][t]);
    __syncthreads();

    f32x4 po[4];
    #pragma unroll
    for (int ni = 0; ni < 4; ++ni) po[ni] = (f32x4){0.f, 0.f, 0.f, 0.f};
    int qrow = wv * 16 + l16;
    #pragma unroll
    for (int ks = 0; ks < 8; ++ks) {
        s16x8 paf = *(const s16x8*)(&p_lds[qrow * 256 + ((ks * 32 + l4 * 8) ^ ((qrow & 7) << 3))]);
        #pragma unroll
        for (int ni = 0; ni < 4; ++ni) {
            int rd = ni * 16 + l16;
            s16x8 bf = *(const s16x8*)(&kv_lds[rd * 256 + ((ks * 32 + l4 * 8) ^ ((rd & 7) << 3))]);
            po[ni] = __builtin_amdgcn_mfma_f32_16x16x32_bf16(paf, bf, po[ni], 0, 0, 0);
        }
    }
    #pragma unroll
    for (int ni = 0; ni < 4; ++ni) {
        int d = ni * 16 + l16;
        #pragma unroll
        for (int rr = 0; rr < 4; ++rr) {
            int row = wv * 16 + l4 * 4 + rr;
            Ab[(size_t)(bm + row) * 512 + d] = f2b(po[ni][rr] * sinv[row]);
        }
    }
}

// ================= batched conv (1,3) + 8->8 mix, 5 groups — VECTORIZED x8 =====
struct ConvArgs {
    const unsigned short* in[5];
    unsigned short* out[5];
    const float* cw[5];
    const float* cb[5];
    int mode[5];
};

__global__ __launch_bounds__(256) void conv5_kernel(ConvArgs a) {
    int g = blockIdx.y;
    __shared__ float scw[192]; __shared__ float scb[8];
    int t = threadIdx.x;
    if (t < 192) scw[t] = a.cw[g][t];
    if (t >= 192 && t < 200) scb[t - 192] = a.cb[g][t - 192];
    __syncthreads();
    const unsigned short* in = a.in[g];
    unsigned short* out = a.out[g];
    size_t gi = ((size_t)blockIdx.x * 256 + t) * 8;
    int mode = a.mode[g];
    float acc[8][8];
    #pragma unroll
    for (int o = 0; o < 8; ++o)
        #pragma unroll
        for (int jj = 0; jj < 8; ++jj) acc[o][jj] = scb[o];

    if (mode == 0) {
        int w = (int)(gi >> 9);
        bool hm = w > 0, hp = w < 255;
        #pragma unroll
        for (int i = 0; i < 8; ++i) {
            size_t base = (size_t)i * kFW + gi;
            s16x8 vc = *(const s16x8*)(&in[base]);
            s16x8 vm = hm ? *(const s16x8*)(&in[base - 512]) : (s16x8){0,0,0,0,0,0,0,0};
            s16x8 vp = hp ? *(const s16x8*)(&in[base + 512]) : (s16x8){0,0,0,0,0,0,0,0};
            float fm[8], fc[8], fp[8];
            #pragma unroll
            for (int jj = 0; jj < 8; ++jj) {
                fm[jj] = b2f((unsigned short)vm[jj]);
                fc[jj] = b2f((unsigned short)vc[jj]);
                fp[jj] = b2f((unsigned short)vp[jj]);
            }
            #pragma unroll
            for (int o = 0; o < 8; ++o) {
                const float* wp = &scw[(o * 8 + i) * 3];
                #pragma unroll
                for (int jj = 0; jj < 8; ++jj)
                    acc[o][jj] += wp[0] * fm[jj] + wp[1] * fc[jj] + wp[2] * fp[jj];
            }
        }
    } else {
        int w0 = (int)(gi & 255);
        #pragma unroll
        for (int i = 0; i < 8; ++i) {
            size_t base = (size_t)i * kFW + gi;
            s16x8 vc = *(const s16x8*)(&in[base]);
            float em = (w0 > 0) ? b2f(in[base - 1]) : 0.f;
            float ep = (w0 + 8 < 256) ? b2f(in[base + 8]) : 0.f;
            float fc[8];
            #pragma unroll
            for (int jj = 0; jj < 8; ++jj) fc[jj] = b2f((unsigned short)vc[jj]);
            float fm[8], fp[8];
            fm[0] = em;
            #pragma unroll
            for (int jj = 1; jj < 8; ++jj) fm[jj] = fc[jj - 1];
            #pragma unroll
            for (int jj = 0; jj < 7; ++jj) fp[jj] = fc[jj + 1];
            fp[7] = ep;
            #pragma unroll
            for (int o = 0; o < 8; ++o) {
                const float* wp = &scw[(o * 8 + i) * 3];
                #pragma unroll
                for (int jj = 0; jj < 8; ++jj)
                    acc[o][jj] += wp[0] * fm[jj] + wp[1] * fc[jj] + wp[2] * fp[jj];
            }
        }
    }
    #pragma unroll
    for (int o = 0; o < 8; ++o) {
        s16x8 pk;
        #pragma unroll
        for (int jj = 0; jj < 8; ++jj) pk[jj] = (short)f2b(acc[o][jj]);
        *(s16x8*)(&out[(size_t)o * kFW + gi]) = pk;
    }
}

// ================= fused 16->8 mix + conv (CA query path), T layout ===========
__global__ __launch_bounds__(256) void mixconv_kernel(const unsigned short* __restrict__ in,
                                                      const float* __restrict__ dw,
                                                      const float* __restrict__ cw,
                                                      const float* __restrict__ cb,
                                                      unsigned short* __restrict__ out) {
    __shared__ float sdw[128], scw[192], scb[8];
    int t = threadIdx.x;
    if (t < 128) sdw[t] = dw[t];
    if (t >= 128 && t < 136) scb[t - 128] = cb[t - 128];
    if (t < 192) scw[t] = cw[t];
    __syncthreads();
    int gi = blockIdx.x * 256 + t;
    int w = gi >> 9;
    bool hm = w > 0, hp = w < 255;
    float xc[16], xm[16], xp[16];
    #pragma unroll
    for (int cc = 0; cc < 16; ++cc) {
        size_t base = (size_t)cc * kFW + gi;
        xc[cc] = b2f(in[base]);
        xm[cc] = hm ? b2f(in[base - 512]) : 0.f;
        xp[cc] = hp ? b2f(in[base + 512]) : 0.f;
    }
    float mm[8], m0[8], mp[8];
    #pragma unroll
    for (int o = 0; o < 8; ++o) {
        float am = 0.f, a0 = 0.f, ap = 0.f;
        #pragma unroll
        for (int cc = 0; cc < 16; ++cc) {
            float wv = sdw[o * 16 + cc];
            am += wv * xm[cc]; a0 += wv * xc[cc]; ap += wv * xp[cc];
        }
        mm[o] = am; m0[o] = a0; mp[o] = ap;
    }
    #pragma unroll
    for (int o = 0; o < 8; ++o) {
        float acc = scb[o];
        #pragma unroll
        for (int i = 0; i < 8; ++i) {
            const float* wp = &scw[(o * 8 + i) * 3];
            acc += wp[0] * mm[i] + wp[1] * m0[i] + wp[2] * mp[i];
        }
        out[(size_t)o * kFW + gi] = f2b(acc);
    }
}

// ================= FFN1: 24->24 mix + exact GELU, in place — VECTORIZED x4 ====
__global__ __launch_bounds__(256) void gelu24_kernel(unsigned short* __restrict__ z,
                                                     const float* __restrict__ dw) {
    __shared__ float sdw[576];
    int t = threadIdx.x;
    for (int i = t; i < 576; i += 256) sdw[i] = dw[i];
    __syncthreads();
    size_t gi = ((size_t)blockIdx.x * 256 + t) * 4;
    const size_t CH = (size_t)256 * 2048;
    float xv[24][4];
    #pragma unroll
    for (int cc = 0; cc < 24; ++cc) {
        s16x4 v = *(const s16x4*)(&z[cc * CH + gi]);
        #pragma unroll
        for (int jj = 0; jj < 4; ++jj) xv[cc][jj] = b2f((unsigned short)v[jj]);
    }
    #pragma unroll
    for (int o = 0; o < 24; ++o) {
        float s0 = 0.f, s1 = 0.f, s2 = 0.f, s3 = 0.f;
        #pragma unroll
        for (int cc = 0; cc < 24; ++cc) {
            float wv = sdw[o * 24 + cc];
            s0 += wv * xv[cc][0]; s1 += wv * xv[cc][1];
            s2 += wv * xv[cc][2]; s3 += wv * xv[cc][3];
        }
        s0 = 0.5f * s0 * (1.0f + erff(s0 * 0.7071067811865475f));
        s1 = 0.5f * s1 * (1.0f + erff(s1 * 0.7071067811865475f));
        s2 = 0.5f * s2 * (1.0f + erff(s2 * 0.7071067811865475f));
        s3 = 0.5f * s3 * (1.0f + erff(s3 * 0.7071067811865475f));
        s16x4 pk = { (short)f2b(s0), (short)f2b(s1), (short)f2b(s2), (short)f2b(s3) };
        *(s16x4*)(&z[o * CH + gi]) = pk;
    }
}

// ================= FFN2 reduce(4 partials) + 24->8 mix + residual =============
__global__ __launch_bounds__(256) void final_mix_add4(const float* __restrict__ x,
                                                      const float* __restrict__ z2,
                                                      const float* __restrict__ dw,
                                                      float* __restrict__ out) {
    __shared__ float sdw[192];
    int t = threadIdx.x;
    if (t < 192) sdw[t] = dw[t];
    __syncthreads();
    int gi = blockIdx.x * 256 + t;
    const size_t PSZ = (size_t)24 * kFW;
    float xv[24];
    #pragma unroll
    for (int cc = 0; cc < 24; ++cc) {
        size_t o = (size_t)cc * kFW + gi;
        xv[cc] = (z2[o] + z2[PSZ + o]) + (z2[2 * PSZ + o] + z2[3 * PSZ + o]);
    }
    #pragma unroll
    for (int o = 0; o < 8; ++o) {
        float s = 0.f;
        #pragma unroll
        for (int cc = 0; cc < 24; ++cc) s += sdw[o * 24 + cc] * xv[cc];
        out[(size_t)o * kFW + gi] = x[(size_t)o * kFW + gi] + s;
    }
}

// ================= launch =====================================================
extern "C" void kernel_launch(void* const* d_in, const int* in_sizes, int n_in,
                              void* d_out, int out_size, void* d_ws, size_t ws_size,
                              hipStream_t stream) {
    const float* x       = (const float*)d_in[0];
    const float* src     = (const float*)d_in[1];
    const float* ln_g    = (const float*)d_in[2];
    const float* ln_b    = (const float*)d_in[3];
    const float* sa_q_pw = (const float*)d_in[4];
    const float* sa_q_cw = (const float*)d_in[5];
    const float* sa_q_cb = (const float*)d_in[6];
    const float* sa_k_pw = (const float*)d_in[7];
    const float* sa_k_cw = (const float*)d_in[8];
    const float* sa_k_cb = (const float*)d_in[9];
    const float* sa_v_pw = (const float*)d_in[10];
    const float* sa_v_cw = (const float*)d_in[11];
    const float* sa_v_cb = (const float*)d_in[12];
    const float* sa_o_pw = (const float*)d_in[13];
    const float* ca_q_pw = (const float*)d_in[14];
    const float* ca_q_dw = (const float*)d_in[15];
    const float* ca_q_cw = (const float*)d_in[16];
    const float* ca_q_cb = (const float*)d_in[17];
    const float* ca_k_pw = (const float*)d_in[18];
    const float* ca_k_cw = (const float*)d_in[19];
    const float* ca_k_cb = (const float*)d_in[20];
    const float* ca_v_pw = (const float*)d_in[21];
    const float* ca_v_cw = (const float*)d_in[22];
    const float* ca_v_cb = (const float*)d_in[23];
    const float* ca_o_pw = (const float*)d_in[24];
    const float* ffn1_pw = (const float*)d_in[25];
    const float* ffn1_dw = (const float*)d_in[26];
    const float* ffn2_pw = (const float*)d_in[27];
    const float* ffn2_dw = (const float*)d_in[28];

    float* out  = (float*)d_out;
    float* qk1o = out + 1048576;
    float* qk2o = out + 1048576 + 4194304;

    unsigned char* ws = (unsigned char*)d_ws;
    unsigned short* CAT24  = (unsigned short*)(ws + 0);
    unsigned short* hTb    = CAT24;
    unsigned short* saTb   = CAT24 + 8 * (size_t)kFW;
    unsigned short* caTb   = CAT24 + 16 * (size_t)kFW;
    unsigned short* SRCT   = (unsigned short*)(ws + 6291456);
    unsigned short* preQ   = (unsigned short*)(ws + 8388608);
    unsigned short* preK   = (unsigned short*)(ws + 10485760);
    unsigned short* preVsa = (unsigned short*)(ws + 12582912);
    unsigned short* preKca = (unsigned short*)(ws + 14680064);
    unsigned short* preVca = (unsigned short*)(ws + 16777216);
    unsigned short* QT     = (unsigned short*)(ws + 18874368);
    unsigned short* KT     = (unsigned short*)(ws + 20971520);
    unsigned short* VNsa   = (unsigned short*)(ws + 23068672);
    unsigned short* KTca   = (unsigned short*)(ws + 25165824);
    unsigned short* VNca   = (unsigned short*)(ws + 27262976);
    unsigned short* PRE16  = (unsigned short*)(ws + 29360128);
    unsigned short* QTca   = (unsigned short*)(ws + 33554432);
    unsigned short* ATTT   = (unsigned short*)(ws + 35651584);
    // FFN phase (attention scratch dead by then):
    unsigned short* Z0T    = (unsigned short*)(ws + 8388608);   // 25 MB [24][256][2048]
    float*          Z2P    = (float*)(ws + 37748736);           // 4 x 12.6 MB partials

    const float qscale = 0.044194173824159216f;   // 1/sqrt(512)
    dim3 blk(256);
    dim3 blk512(512);

    prep_kernel<<<384, blk, 0, stream>>>(x, ln_g, ln_b, hTb, src, SRCT);

    // ---- batched projections: SA q,k,v + CA k,v + CA q (h half) ----
    WB8 p6;
    p6.s[0] = { sa_q_pw, hTb,  preQ,   2 };
    p6.s[1] = { sa_k_pw, hTb,  preK,   2 };
    p6.s[2] = { sa_v_pw, hTb,  preVsa, 1 };
    p6.s[3] = { ca_k_pw, SRCT, preKca, 2 };
    p6.s[4] = { ca_v_pw, SRCT, preVca, 1 };
    p6.s[5] = { ca_q_pw, hTb,  PRE16,  2 };
    p6.s[6] = p6.s[0]; p6.s[7] = p6.s[0];
    wgemmT<256><<<dim3(384), blk, 0, stream>>>(p6, 512, 512, 512, 262144, kFW, kFW, 0, 3, 8, 1, 1);

    ConvArgs c5;
    c5.in[0] = preQ;   c5.out[0] = QT;   c5.cw[0] = sa_q_cw; c5.cb[0] = sa_q_cb; c5.mode[0] = 0;
    c5.in[1] = preK;   c5.out[1] = KT;   c5.cw[1] = sa_k_cw; c5.cb[1] = sa_k_cb; c5.mode[1] = 0;
    c5.in[2] = preVsa; c5.out[2] = VNsa; c5.cw[2] = sa_v_cw; c5.cb[2] = sa_v_cb; c5.mode[2] = 1;
    c5.in[3] = preKca; c5.out[3] = KTca; c5.cw[3] = ca_k_cw; c5.cb[3] = ca_k_cb; c5.mode[3] = 0;
    c5.in[4] = preVca; c5.out[4] = VNca; c5.cw[4] = ca_v_cw; c5.cb[4] = ca_v_cb; c5.mode[4] = 1;
    conv5_kernel<<<dim3(64, 5), blk, 0, stream>>>(c5);

    // ---- self attention (fused QK+softmax+PV) ----
    attn_kernel<<<dim3(4, 64), blk, 0, stream>>>(QT, KT, VNsa, qk1o, ATTT, qscale);
    WB8 so;
    so.s[0] = { sa_o_pw, ATTT, saTb, 2 };
    for (int i = 1; i < 8; ++i) so.s[i] = so.s[0];
    wgemmT<128><<<dim3(128), blk, 0, stream>>>(so, 512, 512, 512, 262144, kFW, kFW, 0, 8, 8, 2, 1);

    // ---- cross attention ----
    WB8 cq2;
    cq2.s[0] = { ca_q_pw + 8 * 262144, saTb, PRE16 + 8 * (size_t)kFW, 2 };
    for (int i = 1; i < 8; ++i) cq2.s[i] = cq2.s[0];
    wgemmT<128><<<dim3(128), blk, 0, stream>>>(cq2, 512, 512, 512, 262144, kFW, kFW, 0, 8, 8, 2, 1);
    mixconv_kernel<<<512, blk, 0, stream>>>(PRE16, ca_q_dw, ca_q_cw, ca_q_cb, QTca);

    attn_kernel<<<dim3(4, 64), blk, 0, stream>>>(QTca, KTca, VNca, qk2o, ATTT, qscale);
    WB8 co;
    co.s[0] = { ca_o_pw, ATTT, caTb, 2 };
    for (int i = 1; i < 8; ++i) co.s[i] = co.s[0];
    wgemmT<128><<<dim3(128), blk, 0, stream>>>(co, 512, 512, 512, 262144, kFW, kFW, 0, 8, 8, 2, 1);

    // ---- FFN ----
    WB8 f1;
    f1.s[0] = { ffn1_pw, CAT24, Z0T, 2 };
    for (int i = 1; i < 8; ++i) f1.s[i] = f1.s[0];
    wgemm512<<<dim3(384), blk512, 0, stream>>>(f1, 2048, 512, 512, 1048576, kFW, 524288, 0, 8, 16, 1);
    gelu24_kernel<<<512, blk, 0, stream>>>(Z0T, ffn1_dw);
    WB8 f2;
    f2.s[0] = { ffn2_pw, Z0T, Z2P, 0 };
    for (int i = 1; i < 8; ++i) f2.s[i] = f2.s[0];
    wgemm512<<<dim3(384), blk512, 0, stream>>>(f2, 512, 2048, 512, 1048576, 524288, kFW, 3145728, 8, 4, 4);
    final_mix_add4<<<512, blk, 0, stream>>>(x, Z2P, ffn2_dw, out);
}

// Round 15
// 253.560 us; speedup vs baseline: 1.0471x; 1.0365x over previous
//
#include <hip/hip_runtime.h>
#include <math.h>

typedef __attribute__((ext_vector_type(4))) float f32x4;
typedef __attribute__((ext_vector_type(8))) short s16x8;
typedef __attribute__((ext_vector_type(4))) short s16x4;

__device__ __forceinline__ unsigned short f2b(float f) {
    union { float f; unsigned u; } v; v.f = f;
    unsigned r = v.u + 0x7fffu + ((v.u >> 16) & 1u);
    return (unsigned short)(r >> 16);
}
__device__ __forceinline__ float b2f(unsigned short u) {
    union { unsigned u; float f; } v; v.u = ((unsigned)u) << 16;
    return v.f;
}

// global -> LDS direct copy, 16 B per lane. LDS dest = wave-uniform base + lane*16.
__device__ __forceinline__ void gll16(const void* g, void* l) {
    __builtin_amdgcn_global_load_lds((const __attribute__((address_space(1))) unsigned int*)g,
                                     (__attribute__((address_space(3))) unsigned int*)l,
                                     16, 0, 0);
}

constexpr int kF = 512;
constexpr int kW = 256;
constexpr int kFW = kF * kW;   // 131072

// ================= prep: LayerNorm (bid<128) + src transpose (bid>=128) ========
__global__ __launch_bounds__(256) void prep_kernel(const float* __restrict__ x,
                                                   const float* __restrict__ g,
                                                   const float* __restrict__ b,
                                                   unsigned short* __restrict__ hTb,
                                                   const float* __restrict__ src,
                                                   unsigned short* __restrict__ SRCT) {
    __shared__ float tile[64][65];
    __shared__ float s1[16][16], s2[16][16];
    int bid = blockIdx.x;
    int t = threadIdx.x;
    if (bid < 128) {
        int c = bid >> 4;
        int w0 = (bid & 15) * 16;
        int wi = t & 15, fg = t >> 4;
        const float* xb = x + (size_t)c * kFW + w0 + wi;
        float sum = 0.f, sum2 = 0.f;
        for (int j = 0; j < 32; ++j) {
            float v = xb[(size_t)(fg * 32 + j) * kW];
            sum += v; sum2 += v * v;
        }
        s1[fg][wi] = sum; s2[fg][wi] = sum2;
        __syncthreads();
        float ts = 0.f, tq = 0.f;
        #pragma unroll
        for (int j = 0; j < 16; ++j) { ts += s1[j][wi]; tq += s2[j][wi]; }
        float mu = ts * (1.0f / 512.0f);
        float rstd = rsqrtf(tq * (1.0f / 512.0f) - mu * mu + 1e-5f);
        const float* gc = g + c * kF + fg * 32;
        const float* bc = b + c * kF + fg * 32;
        unsigned short* ob = hTb + (size_t)c * kFW + (size_t)(w0 + wi) * kF + fg * 32;
        for (int j = 0; j < 32; j += 4) {
            float v0 = xb[(size_t)(fg * 32 + j + 0) * kW];
            float v1 = xb[(size_t)(fg * 32 + j + 1) * kW];
            float v2 = xb[(size_t)(fg * 32 + j + 2) * kW];
            float v3 = xb[(size_t)(fg * 32 + j + 3) * kW];
            s16x4 p = { (short)f2b((v0 - mu) * rstd * gc[j + 0] + bc[j + 0]),
                        (short)f2b((v1 - mu) * rstd * gc[j + 1] + bc[j + 1]),
                        (short)f2b((v2 - mu) * rstd * gc[j + 2] + bc[j + 2]),
                        (short)f2b((v3 - mu) * rstd * gc[j + 3] + bc[j + 3]) };
            *(s16x4*)(&ob[j]) = p;
        }
    } else {
        int fid = bid - 128;
        int c = fid >> 5;
        int f0 = ((fid >> 2) & 7) * 64, w0 = (fid & 3) * 64;
        int tw = t & 63, tf4 = t >> 6;
        for (int i = 0; i < 16; ++i) {
            int f = tf4 * 16 + i;
            tile[f][tw] = src[(size_t)c * kFW + (size_t)(f0 + f) * kW + w0 + tw];
        }
        __syncthreads();
        int w = t >> 2, fc = (t & 3) * 16;
        unsigned short* ob = SRCT + (size_t)c * kFW + (size_t)(w0 + w) * kF + f0 + fc;
        for (int j = 0; j < 16; j += 4) {
            s16x4 p = { (short)f2b(tile[fc + j + 0][w]), (short)f2b(tile[fc + j + 1][w]),
                        (short)f2b(tile[fc + j + 2][w]), (short)f2b(tile[fc + j + 3][w]) };
            *(s16x4*)(&ob[j]) = p;
        }
    }
}

// ================= weight-streaming GEMM, single-buffer gll (round-8 skeleton) =
// omode: 0 = f32 [m][n] (+kz*c_split), 1 = bf16 [m][n], 2 = bf16 T [n][m]
struct WSeg { const float* A; const unsigned short* B; void* C; int omode; };
struct WB8 { WSeg s[8]; };

template<int BN>
__global__ __launch_bounds__(256) void wgemmT(WB8 wb, int M, int K, int Klocal,
                                              long a_ch, long b_ch, long c_ch, long c_split,
                                              int segshift, int nm, int ntiles, int ksplit) {
    constexpr int NF = BN / 16;
    constexpr int RPW = BN / 4;
    constexpr int GP = BN / 32;
    __shared__ unsigned short lds[BN * 64];

    int t = threadIdx.x, lane = t & 63, wv = t >> 6;
    int l16 = lane & 15, l4 = lane >> 4;

    int id = blockIdx.x;
    int r = id & 7, j = id >> 3;
    int per = nm * ntiles * ksplit;
    int y = r + 8 * (j / per);
    int rem = j % per;
    int mt = rem % nm;
    int rem2 = rem / nm;
    int ntile = rem2 % ntiles;
    int kz = rem2 / ntiles;
    int seg = y >> segshift, c = y & ((1 << segshift) - 1);
    WSeg sg = wb.s[seg];
    int bm = mt * 64;
    int bn = ntile * BN;
    int kbase = kz * Klocal;

    const float* A = sg.A + (size_t)c * a_ch + kbase;
    const unsigned short* Bc = sg.B + (size_t)c * b_ch + kbase;
    const float* arow = A + (size_t)(bm + wv * 16 + l16) * K + l4 * 8;

    int rsub = lane >> 3;
    int gsw = ((lane & 7) ^ rsub) * 8;
    const unsigned short* bsrc = Bc + (size_t)(bn + wv * RPW + rsub) * K + gsw;

    f32x4 acc[NF];
    #pragma unroll
    for (int i = 0; i < NF; ++i) acc[i] = (f32x4){0.f, 0.f, 0.f, 0.f};

    f32x4 pa0 = __builtin_nontemporal_load((const f32x4*)arow);
    f32x4 pa1 = __builtin_nontemporal_load((const f32x4*)(arow + 4));

    for (int kc = 0; kc < Klocal; kc += 64) {
        if (kc) __syncthreads();
        #pragma unroll
        for (int i = 0; i < GP; ++i) {
            int r0 = wv * RPW + i * 8;
            gll16(bsrc + (size_t)(i * 8) * K + kc, (char*)lds + (r0 << 7));
        }
        __syncthreads();
        #pragma unroll
        for (int ks = 0; ks < 2; ++ks) {
            f32x4 c0 = pa0, c1 = pa1;
            int nk = kc + (ks + 1) * 32;
            if (nk < Klocal) {
                pa0 = __builtin_nontemporal_load((const f32x4*)(arow + nk));
                pa1 = __builtin_nontemporal_load((const f32x4*)(arow + nk + 4));
            }
            s16x8 af = { (short)f2b(c0.x), (short)f2b(c0.y), (short)f2b(c0.z), (short)f2b(c0.w),
                         (short)f2b(c1.x), (short)f2b(c1.y), (short)f2b(c1.z), (short)f2b(c1.w) };
            #pragma unroll
            for (int ni = 0; ni < NF; ++ni) {
                int rr = ni * 16 + l16;
                s16x8 bf = *(const s16x8*)(&lds[rr * 64 + ((ks * 32 + l4 * 8) ^ ((rr & 7) << 3))]);
                acc[ni] = __builtin_amdgcn_mfma_f32_16x16x32_bf16(af, bf, acc[ni], 0, 0, 0);
            }
        }
    }

    int m0 = bm + wv * 16 + l4 * 4;
    if (sg.omode == 2) {
        unsigned short* C = (unsigned short*)sg.C + (size_t)c * c_ch;
        #pragma unroll
        for (int ni = 0; ni < NF; ++ni) {
            int n = bn + ni * 16 + l16;
            s16x4 pk = { (short)f2b(acc[ni][0]), (short)f2b(acc[ni][1]),
                         (short)f2b(acc[ni][2]), (short)f2b(acc[ni][3]) };
            *(s16x4*)(&C[(size_t)n * M + m0]) = pk;
        }
    } else if (sg.omode == 1) {
        unsigned short* C = (unsigned short*)sg.C + (size_t)c * c_ch;
        #pragma unroll
        for (int ni = 0; ni < NF; ++ni) {
            int n = bn + ni * 16 + l16;
            #pragma unroll
            for (int rr = 0; rr < 4; ++rr)
                C[(size_t)(m0 + rr) * 256 + n] = f2b(acc[ni][rr]);
        }
    } else {
        float* C = (float*)sg.C + (size_t)c * c_ch + (size_t)kz * c_split;
        #pragma unroll
        for (int ni = 0; ni < NF; ++ni) {
            int n = bn + ni * 16 + l16;
            #pragma unroll
            for (int rr = 0; rr < 4; ++rr)
                C[(size_t)(m0 + rr) * 256 + n] = acc[ni][rr];
        }
    }
}

// ================= big-GEMM variant: 128m x 256n, 512 thr, dbuf issue-ahead ===
__global__ __launch_bounds__(512) void wgemm512(WB8 wb, int M, int K, int Klocal,
                                                long a_ch, long b_ch, long c_ch, long c_split,
                                                int segshift, int nm, int ksplit) {
    __shared__ unsigned short lds[2][16384];
    int t = threadIdx.x, lane = t & 63, wv = t >> 6;
    int l16 = lane & 15, l4 = lane >> 4;

    int id = blockIdx.x;
    int r = id & 7, j = id >> 3;
    int per = nm * ksplit;
    int y = r + 8 * (j / per);
    int rem = j % per;
    int mt = rem % nm;
    int kz = rem / nm;
    int seg = y >> segshift, c = y & ((1 << segshift) - 1);
    WSeg sg = wb.s[seg];
    int bm = mt * 128;
    int kbase = kz * Klocal;

    const float* A = sg.A + (size_t)c * a_ch + kbase;
    const unsigned short* Bc = sg.B + (size_t)c * b_ch + kbase;
    const float* arow = A + (size_t)(bm + wv * 16 + l16) * K + l4 * 8;

    int rsub = lane >> 3;
    int gsw = ((lane & 7) ^ rsub) * 8;
    const unsigned short* bsrc = Bc + (size_t)(wv * 32 + rsub) * K + gsw;

    f32x4 acc[16];
    #pragma unroll
    for (int i = 0; i < 16; ++i) acc[i] = (f32x4){0.f, 0.f, 0.f, 0.f};

    #pragma unroll
    for (int i = 0; i < 4; ++i)
        gll16(bsrc + (size_t)(i * 8) * K, (char*)lds[0] + ((wv * 32 + i * 8) << 7));

    f32x4 pa0 = __builtin_nontemporal_load((const f32x4*)arow);
    f32x4 pa1 = __builtin_nontemporal_load((const f32x4*)(arow + 4));

    int nc = Klocal >> 6;
    for (int cc = 0; cc < nc; ++cc) {
        __syncthreads();
        if (cc + 1 < nc) {
            int kc = (cc + 1) * 64;
            #pragma unroll
            for (int i = 0; i < 4; ++i)
                gll16(bsrc + (size_t)(i * 8) * K + kc,
                      (char*)lds[(cc + 1) & 1] + ((wv * 32 + i * 8) << 7));
        }
        const unsigned short* buf = lds[cc & 1];
        #pragma unroll
        for (int ks = 0; ks < 2; ++ks) {
            f32x4 c0 = pa0, c1 = pa1;
            int nk = cc * 64 + (ks + 1) * 32;
            if (nk < Klocal) {
                pa0 = __builtin_nontemporal_load((const f32x4*)(arow + nk));
                pa1 = __builtin_nontemporal_load((const f32x4*)(arow + nk + 4));
            }
            s16x8 af = { (short)f2b(c0.x), (short)f2b(c0.y), (short)f2b(c0.z), (short)f2b(c0.w),
                         (short)f2b(c1.x), (short)f2b(c1.y), (short)f2b(c1.z), (short)f2b(c1.w) };
            #pragma unroll
            for (int ni = 0; ni < 16; ++ni) {
                int rr = ni * 16 + l16;
                s16x8 bf = *(const s16x8*)(&buf[rr * 64 + ((ks * 32 + l4 * 8) ^ ((rr & 7) << 3))]);
                acc[ni] = __builtin_amdgcn_mfma_f32_16x16x32_bf16(af, bf, acc[ni], 0, 0, 0);
            }
        }
    }

    int m0 = bm + wv * 16 + l4 * 4;
    if (sg.omode == 2) {
        unsigned short* C = (unsigned short*)sg.C + (size_t)c * c_ch;
        #pragma unroll
        for (int ni = 0; ni < 16; ++ni) {
            int n = ni * 16 + l16;
            s16x4 pk = { (short)f2b(acc[ni][0]), (short)f2b(acc[ni][1]),
                         (short)f2b(acc[ni][2]), (short)f2b(acc[ni][3]) };
            *(s16x4*)(&C[(size_t)n * M + m0]) = pk;
        }
    } else if (sg.omode == 1) {
        unsigned short* C = (unsigned short*)sg.C + (size_t)c * c_ch;
        #pragma unroll
        for (int ni = 0; ni < 16; ++ni) {
            int n = ni * 16 + l16;
            #pragma unroll
            for (int rr = 0; rr < 4; ++rr)
                C[(size_t)(m0 + rr) * 256 + n] = f2b(acc[ni][rr]);
        }
    } else {
        float* C = (float*)sg.C + (size_t)c * c_ch + (size_t)kz * c_split;
        #pragma unroll
        for (int ni = 0; ni < 16; ++ni) {
            int n = ni * 16 + l16;
            #pragma unroll
            for (int rr = 0; rr < 4; ++rr)
                C[(size_t)(m0 + rr) * 256 + n] = acc[ni][rr];
        }
    }
}

// ================= fused attention: QK^T + softmax + PV =======================
__global__ __launch_bounds__(256) void attn_kernel(
    const unsigned short* __restrict__ Qt, const unsigned short* __restrict__ Kt,
    const unsigned short* __restrict__ VN, float* __restrict__ S,
    unsigned short* __restrict__ ATTT, float scale)
{
    __shared__ unsigned short q_lds[4096];
    __shared__ unsigned short kv_lds[16384];
    __shared__ unsigned short p_lds[16384];
    __shared__ float smax[4][64], ssum[4][64], sinv[64];
    int t = threadIdx.x, lane = t & 63, wv = t >> 6;
    int l16 = lane & 15, l4 = lane >> 4;
    int ch = blockIdx.y, c = ch >> 3, h = ch & 7;
    int bm = blockIdx.x * 64;
    const unsigned short* Qb = Qt + (size_t)c * kFW + h * 64;
    const unsigned short* Kb = Kt + (size_t)c * kFW + h * 64;
    const unsigned short* Vb = VN + (size_t)c * kFW + (size_t)(h * 64) * 256;
    float* Sb = S + (size_t)ch * 65536;
    unsigned short* Ab = ATTT + (size_t)c * kFW + h * 64;

    s16x8 qr[2], kr[8], vr[8];
    #pragma unroll
    for (int i = 0; i < 2; ++i) {
        int idx = i * 256 + t; int rr = idx >> 3, ck = idx & 7;
        qr[i] = *(const s16x8*)(Qb + (size_t)(bm + rr) * 512 + ck * 8);
    }
    #pragma unroll
    for (int i = 0; i < 8; ++i) {
        int idx = i * 256 + t; int rr = idx >> 3, ck = idx & 7;
        kr[i] = *(const s16x8*)(Kb + (size_t)rr * 512 + ck * 8);
    }
    #pragma unroll
    for (int i = 0; i < 8; ++i) {
        int idx = i * 256 + t; int d = idx >> 5, cs = idx & 31;
        vr[i] = *(const s16x8*)(Vb + (size_t)d * 256 + cs * 8);
    }
    #pragma unroll
    for (int i = 0; i < 2; ++i) {
        int idx = i * 256 + t; int rr = idx >> 3, ck = idx & 7;
        *(s16x8*)(&q_lds[rr * 64 + ((ck * 8) ^ ((rr & 7) << 3))]) = qr[i];
    }
    #pragma unroll
    for (int i = 0; i < 8; ++i) {
        int idx = i * 256 + t; int rr = idx >> 3, ck = idx & 7;
        *(s16x8*)(&kv_lds[rr * 64 + ((ck * 8) ^ ((rr & 7) << 3))]) = kr[i];
    }
    __syncthreads();

    f32x4 acc[4][4];
    #pragma unroll
    for (int i = 0; i < 4; ++i)
        #pragma unroll
        for (int jj = 0; jj < 4; ++jj) acc[i][jj] = (f32x4){0.f, 0.f, 0.f, 0.f};
    #pragma unroll
    for (int ks = 0; ks < 2; ++ks) {
        s16x8 af[4], bfr[4];
        #pragma unroll
        for (int mi = 0; mi < 4; ++mi) {
            int rq = mi * 16 + l16;
            af[mi] = *(const s16x8*)(&q_lds[rq * 64 + ((ks * 32 + l4 * 8) ^ ((rq & 7) << 3))]);
        }
        #pragma unroll
        for (int ni = 0; ni < 4; ++ni) {
            int rk = wv * 64 + ni * 16 + l16;
            bfr[ni] = *(const s16x8*)(&kv_lds[rk * 64 + ((ks * 32 + l4 * 8) ^ ((rk & 7) << 3))]);
        }
        #pragma unroll
        for (int mi = 0; mi < 4; ++mi)
            #pragma unroll
            for (int ni = 0; ni < 4; ++ni)
                acc[mi][ni] = __builtin_amdgcn_mfma_f32_16x16x32_bf16(af[mi], bfr[ni], acc[mi][ni], 0, 0, 0);
    }

    #pragma unroll
    for (int mi = 0; mi < 4; ++mi)
        #pragma unroll
        for (int ni = 0; ni < 4; ++ni) {
            acc[mi][ni] *= scale;
            int col = wv * 64 + ni * 16 + l16;
            int row0 = bm + mi * 16 + l4 * 4;
            #pragma unroll
            for (int rr = 0; rr < 4; ++rr)
                Sb[(size_t)(row0 + rr) * 256 + col] = acc[mi][ni][rr];
        }

    float rmax[4][4];
    #pragma unroll
    for (int mi = 0; mi < 4; ++mi)
        #pragma unroll
        for (int rr = 0; rr < 4; ++rr)
            rmax[mi][rr] = fmaxf(fmaxf(acc[mi][0][rr], acc[mi][1][rr]), fmaxf(acc[mi][2][rr], acc[mi][3][rr]));
    #pragma unroll
    for (int d = 1; d < 16; d <<= 1)
        #pragma unroll
        for (int mi = 0; mi < 4; ++mi)
            #pragma unroll
            for (int rr = 0; rr < 4; ++rr)
                rmax[mi][rr] = fmaxf(rmax[mi][rr], __shfl_xor(rmax[mi][rr], d));
    if (l16 == 0)
        #pragma unroll
        for (int mi = 0; mi < 4; ++mi)
            #pragma unroll
            for (int rr = 0; rr < 4; ++rr)
                smax[wv][mi * 16 + l4 * 4 + rr] = rmax[mi][rr];
    __syncthreads();
    float rsum[4][4];
    #pragma unroll
    for (int mi = 0; mi < 4; ++mi)
        #pragma unroll
        for (int rr = 0; rr < 4; ++rr) {
            int row = mi * 16 + l4 * 4 + rr;
            float rM = fmaxf(fmaxf(smax[0][row], smax[1][row]), fmaxf(smax[2][row], smax[3][row]));
            rsum[mi][rr] = 0.f;
            #pragma unroll
            for (int ni = 0; ni < 4; ++ni) {
                float e = __expf(acc[mi][ni][rr] - rM);
                acc[mi][ni][rr] = e;
                rsum[mi][rr] += e;
            }
        }
    #pragma unroll
    for (int d = 1; d < 16; d <<= 1)
        #pragma unroll
        for (int mi = 0; mi < 4; ++mi)
            #pragma unroll
            for (int rr = 0; rr < 4; ++rr)
                rsum[mi][rr] += __shfl_xor(rsum[mi][rr], d);
    if (l16 == 0)
        #pragma unroll
        for (int mi = 0; mi < 4; ++mi)
            #pragma unroll
            for (int rr = 0; rr < 4; ++rr)
                ssum[wv][mi * 16 + l4 * 4 + rr] = rsum[mi][rr];
    __syncthreads();

    #pragma unroll
    for (int i = 0; i < 8; ++i) {
        int idx = i * 256 + t; int d = idx >> 5, cs = idx & 31;
        *(s16x8*)(&kv_lds[d * 256 + ((cs * 8) ^ ((d & 7) << 3))]) = vr[i];
    }
    #pragma unroll
    for (int mi = 0; mi < 4; ++mi)
        #pragma unroll
        for (int ni = 0; ni < 4; ++ni) {
            int col = wv * 64 + ni * 16 + l16;
            int cb = col & ~7, cl = col & 7;
            #pragma unroll
            for (int rr = 0; rr < 4; ++rr) {
                int row = mi * 16 + l4 * 4 + rr;
                p_lds[row * 256 + (cb ^ ((row & 7) << 3)) + cl] = f2b(acc[mi][ni][rr]);
            }
        }
    if (t < 64) sinv[t] = 1.f / (ssum[0][t] + ssum[1][t] + ssum[2][t] + ssum[3][t]);
    __syncthreads();

    f32x4 po[4];
    #pragma unroll
    for (int ni = 0; ni < 4; ++ni) po[ni] = (f32x4){0.f, 0.f, 0.f, 0.f};
    int qrow = wv * 16 + l16;
    #pragma unroll
    for (int ks = 0; ks < 8; ++ks) {
        s16x8 paf = *(const s16x8*)(&p_lds[qrow * 256 + ((ks * 32 + l4 * 8) ^ ((qrow & 7) << 3))]);
        #pragma unroll
        for (int ni = 0; ni < 4; ++ni) {
            int rd = ni * 16 + l16;
            s16x8 bf = *(const s16x8*)(&kv_lds[rd * 256 + ((ks * 32 + l4 * 8) ^ ((rd & 7) << 3))]);
            po[ni] = __builtin_amdgcn_mfma_f32_16x16x32_bf16(paf, bf, po[ni], 0, 0, 0);
        }
    }
    #pragma unroll
    for (int ni = 0; ni < 4; ++ni) {
        int d = ni * 16 + l16;
        #pragma unroll
        for (int rr = 0; rr < 4; ++rr) {
            int row = wv * 16 + l4 * 4 + rr;
            Ab[(size_t)(bm + row) * 512 + d] = f2b(po[ni][rr] * sinv[row]);
        }
    }
}

// ================= batched conv (1,3) + 8->8 mix, 5 groups — VECTORIZED x8 =====
struct ConvArgs {
    const unsigned short* in[5];
    unsigned short* out[5];
    const float* cw[5];
    const float* cb[5];
    int mode[5];
};

__global__ __launch_bounds__(256) void conv5_kernel(ConvArgs a) {
    int g = blockIdx.y;
    __shared__ float scw[192]; __shared__ float scb[8];
    int t = threadIdx.x;
    if (t < 192) scw[t] = a.cw[g][t];
    if (t >= 192 && t < 200) scb[t - 192] = a.cb[g][t - 192];
    __syncthreads();
    const unsigned short* in = a.in[g];
    unsigned short* out = a.out[g];
    size_t gi = ((size_t)blockIdx.x * 256 + t) * 8;
    int mode = a.mode[g];
    float acc[8][8];
    #pragma unroll
    for (int o = 0; o < 8; ++o)
        #pragma unroll
        for (int jj = 0; jj < 8; ++jj) acc[o][jj] = scb[o];

    if (mode == 0) {
        int w = (int)(gi >> 9);
        bool hm = w > 0, hp = w < 255;
        #pragma unroll
        for (int i = 0; i < 8; ++i) {
            size_t base = (size_t)i * kFW + gi;
            s16x8 vc = *(const s16x8*)(&in[base]);
            s16x8 vm = hm ? *(const s16x8*)(&in[base - 512]) : (s16x8){0,0,0,0,0,0,0,0};
            s16x8 vp = hp ? *(const s16x8*)(&in[base + 512]) : (s16x8){0,0,0,0,0,0,0,0};
            float fm[8], fc[8], fp[8];
            #pragma unroll
            for (int jj = 0; jj < 8; ++jj) {
                fm[jj] = b2f((unsigned short)vm[jj]);
                fc[jj] = b2f((unsigned short)vc[jj]);
                fp[jj] = b2f((unsigned short)vp[jj]);
            }
            #pragma unroll
            for (int o = 0; o < 8; ++o) {
                const float* wp = &scw[(o * 8 + i) * 3];
                #pragma unroll
                for (int jj = 0; jj < 8; ++jj)
                    acc[o][jj] += wp[0] * fm[jj] + wp[1] * fc[jj] + wp[2] * fp[jj];
            }
        }
    } else {
        int w0 = (int)(gi & 255);
        #pragma unroll
        for (int i = 0; i < 8; ++i) {
            size_t base = (size_t)i * kFW + gi;
            s16x8 vc = *(const s16x8*)(&in[base]);
            float em = (w0 > 0) ? b2f(in[base - 1]) : 0.f;
            float ep = (w0 + 8 < 256) ? b2f(in[base + 8]) : 0.f;
            float fc[8];
            #pragma unroll
            for (int jj = 0; jj < 8; ++jj) fc[jj] = b2f((unsigned short)vc[jj]);
            float fm[8], fp[8];
            fm[0] = em;
            #pragma unroll
            for (int jj = 1; jj < 8; ++jj) fm[jj] = fc[jj - 1];
            #pragma unroll
            for (int jj = 0; jj < 7; ++jj) fp[jj] = fc[jj + 1];
            fp[7] = ep;
            #pragma unroll
            for (int o = 0; o < 8; ++o) {
                const float* wp = &scw[(o * 8 + i) * 3];
                #pragma unroll
                for (int jj = 0; jj < 8; ++jj)
                    acc[o][jj] += wp[0] * fm[jj] + wp[1] * fc[jj] + wp[2] * fp[jj];
            }
        }
    }
    #pragma unroll
    for (int o = 0; o < 8; ++o) {
        s16x8 pk;
        #pragma unroll
        for (int jj = 0; jj < 8; ++jj) pk[jj] = (short)f2b(acc[o][jj]);
        *(s16x8*)(&out[(size_t)o * kFW + gi]) = pk;
    }
}

// ================= fused 16->8 mix + conv (CA query path), T layout ===========
__global__ __launch_bounds__(256) void mixconv_kernel(const unsigned short* __restrict__ in,
                                                      const float* __restrict__ dw,
                                                      const float* __restrict__ cw,
                                                      const float* __restrict__ cb,
                                                      unsigned short* __restrict__ out) {
    __shared__ float sdw[128], scw[192], scb[8];
    int t = threadIdx.x;
    if (t < 128) sdw[t] = dw[t];
    if (t >= 128 && t < 136) scb[t - 128] = cb[t - 128];
    if (t < 192) scw[t] = cw[t];
    __syncthreads();
    int gi = blockIdx.x * 256 + t;
    int w = gi >> 9;
    bool hm = w > 0, hp = w < 255;
    float xc[16], xm[16], xp[16];
    #pragma unroll
    for (int cc = 0; cc < 16; ++cc) {
        size_t base = (size_t)cc * kFW + gi;
        xc[cc] = b2f(in[base]);
        xm[cc] = hm ? b2f(in[base - 512]) : 0.f;
        xp[cc] = hp ? b2f(in[base + 512]) : 0.f;
    }
    float mm[8], m0[8], mp[8];
    #pragma unroll
    for (int o = 0; o < 8; ++o) {
        float am = 0.f, a0 = 0.f, ap = 0.f;
        #pragma unroll
        for (int cc = 0; cc < 16; ++cc) {
            float wv = sdw[o * 16 + cc];
            am += wv * xm[cc]; a0 += wv * xc[cc]; ap += wv * xp[cc];
        }
        mm[o] = am; m0[o] = a0; mp[o] = ap;
    }
    #pragma unroll
    for (int o = 0; o < 8; ++o) {
        float acc = scb[o];
        #pragma unroll
        for (int i = 0; i < 8; ++i) {
            const float* wp = &scw[(o * 8 + i) * 3];
            acc += wp[0] * mm[i] + wp[1] * m0[i] + wp[2] * mp[i];
        }
        out[(size_t)o * kFW + gi] = f2b(acc);
    }
}

// ================= FFN1: 24->24 mix + exact GELU, in place — VECTORIZED x4 ====
__global__ __launch_bounds__(256) void gelu24_kernel(unsigned short* __restrict__ z,
                                                     const float* __restrict__ dw) {
    __shared__ float sdw[576];
    int t = threadIdx.x;
    for (int i = t; i < 576; i += 256) sdw[i] = dw[i];
    __syncthreads();
    size_t gi = ((size_t)blockIdx.x * 256 + t) * 4;
    const size_t CH = (size_t)256 * 2048;
    float xv[24][4];
    #pragma unroll
    for (int cc = 0; cc < 24; ++cc) {
        s16x4 v = *(const s16x4*)(&z[cc * CH + gi]);
        #pragma unroll
        for (int jj = 0; jj < 4; ++jj) xv[cc][jj] = b2f((unsigned short)v[jj]);
    }
    #pragma unroll
    for (int o = 0; o < 24; ++o) {
        float s0 = 0.f, s1 = 0.f, s2 = 0.f, s3 = 0.f;
        #pragma unroll
        for (int cc = 0; cc < 24; ++cc) {
            float wv = sdw[o * 24 + cc];
            s0 += wv * xv[cc][0]; s1 += wv * xv[cc][1];
            s2 += wv * xv[cc][2]; s3 += wv * xv[cc][3];
        }
        s0 = 0.5f * s0 * (1.0f + erff(s0 * 0.7071067811865475f));
        s1 = 0.5f * s1 * (1.0f + erff(s1 * 0.7071067811865475f));
        s2 = 0.5f * s2 * (1.0f + erff(s2 * 0.7071067811865475f));
        s3 = 0.5f * s3 * (1.0f + erff(s3 * 0.7071067811865475f));
        s16x4 pk = { (short)f2b(s0), (short)f2b(s1), (short)f2b(s2), (short)f2b(s3) };
        *(s16x4*)(&z[o * CH + gi]) = pk;
    }
}

// ================= FFN2 reduce(2 partials) + 24->8 mix + residual =============
__global__ __launch_bounds__(256) void final_mix_add2(const float* __restrict__ x,
                                                      const float* __restrict__ z2,
                                                      const float* __restrict__ dw,
                                                      float* __restrict__ out) {
    __shared__ float sdw[192];
    int t = threadIdx.x;
    if (t < 192) sdw[t] = dw[t];
    __syncthreads();
    int gi = blockIdx.x * 256 + t;
    const size_t PSZ = (size_t)24 * kFW;
    float xv[24];
    #pragma unroll
    for (int cc = 0; cc < 24; ++cc) {
        size_t o = (size_t)cc * kFW + gi;
        xv[cc] = z2[o] + z2[PSZ + o];
    }
    #pragma unroll
    for (int o = 0; o < 8; ++o) {
        float s = 0.f;
        #pragma unroll
        for (int cc = 0; cc < 24; ++cc) s += sdw[o * 24 + cc] * xv[cc];
        out[(size_t)o * kFW + gi] = x[(size_t)o * kFW + gi] + s;
    }
}

// ================= launch =====================================================
extern "C" void kernel_launch(void* const* d_in, const int* in_sizes, int n_in,
                              void* d_out, int out_size, void* d_ws, size_t ws_size,
                              hipStream_t stream) {
    const float* x       = (const float*)d_in[0];
    const float* src     = (const float*)d_in[1];
    const float* ln_g    = (const float*)d_in[2];
    const float* ln_b    = (const float*)d_in[3];
    const float* sa_q_pw = (const float*)d_in[4];
    const float* sa_q_cw = (const float*)d_in[5];
    const float* sa_q_cb = (const float*)d_in[6];
    const float* sa_k_pw = (const float*)d_in[7];
    const float* sa_k_cw = (const float*)d_in[8];
    const float* sa_k_cb = (const float*)d_in[9];
    const float* sa_v_pw = (const float*)d_in[10];
    const float* sa_v_cw = (const float*)d_in[11];
    const float* sa_v_cb = (const float*)d_in[12];
    const float* sa_o_pw = (const float*)d_in[13];
    const float* ca_q_pw = (const float*)d_in[14];
    const float* ca_q_dw = (const float*)d_in[15];
    const float* ca_q_cw = (const float*)d_in[16];
    const float* ca_q_cb = (const float*)d_in[17];
    const float* ca_k_pw = (const float*)d_in[18];
    const float* ca_k_cw = (const float*)d_in[19];
    const float* ca_k_cb = (const float*)d_in[20];
    const float* ca_v_pw = (const float*)d_in[21];
    const float* ca_v_cw = (const float*)d_in[22];
    const float* ca_v_cb = (const float*)d_in[23];
    const float* ca_o_pw = (const float*)d_in[24];
    const float* ffn1_pw = (const float*)d_in[25];
    const float* ffn1_dw = (const float*)d_in[26];
    const float* ffn2_pw = (const float*)d_in[27];
    const float* ffn2_dw = (const float*)d_in[28];

    float* out  = (float*)d_out;
    float* qk1o = out + 1048576;
    float* qk2o = out + 1048576 + 4194304;

    unsigned char* ws = (unsigned char*)d_ws;
    unsigned short* CAT24  = (unsigned short*)(ws + 0);
    unsigned short* hTb    = CAT24;
    unsigned short* saTb   = CAT24 + 8 * (size_t)kFW;
    unsigned short* caTb   = CAT24 + 16 * (size_t)kFW;
    unsigned short* SRCT   = (unsigned short*)(ws + 6291456);
    unsigned short* preQ   = (unsigned short*)(ws + 8388608);
    unsigned short* preK   = (unsigned short*)(ws + 10485760);
    unsigned short* preVsa = (unsigned short*)(ws + 12582912);
    unsigned short* preKca = (unsigned short*)(ws + 14680064);
    unsigned short* preVca = (unsigned short*)(ws + 16777216);
    unsigned short* QT     = (unsigned short*)(ws + 18874368);
    unsigned short* KT     = (unsigned short*)(ws + 20971520);
    unsigned short* VNsa   = (unsigned short*)(ws + 23068672);
    unsigned short* KTca   = (unsigned short*)(ws + 25165824);
    unsigned short* VNca   = (unsigned short*)(ws + 27262976);
    unsigned short* PRE16  = (unsigned short*)(ws + 29360128);
    unsigned short* QTca   = (unsigned short*)(ws + 33554432);
    unsigned short* ATTT   = (unsigned short*)(ws + 35651584);
    // FFN phase (attention scratch dead by then):
    unsigned short* Z0T    = (unsigned short*)(ws + 8388608);
    float*          Z2P    = (float*)(ws + 37748736);

    const float qscale = 0.044194173824159216f;   // 1/sqrt(512)
    dim3 blk(256);
    dim3 blk512(512);

    prep_kernel<<<384, blk, 0, stream>>>(x, ln_g, ln_b, hTb, src, SRCT);

    // ---- batched projections: SA q,k,v + CA k,v + CA q (h half) ----
    WB8 p6;
    p6.s[0] = { sa_q_pw, hTb,  preQ,   2 };
    p6.s[1] = { sa_k_pw, hTb,  preK,   2 };
    p6.s[2] = { sa_v_pw, hTb,  preVsa, 1 };
    p6.s[3] = { ca_k_pw, SRCT, preKca, 2 };
    p6.s[4] = { ca_v_pw, SRCT, preVca, 1 };
    p6.s[5] = { ca_q_pw, hTb,  PRE16,  2 };
    p6.s[6] = p6.s[0]; p6.s[7] = p6.s[0];
    wgemmT<256><<<dim3(384), blk, 0, stream>>>(p6, 512, 512, 512, 262144, kFW, kFW, 0, 3, 8, 1, 1);

    ConvArgs c5;
    c5.in[0] = preQ;   c5.out[0] = QT;   c5.cw[0] = sa_q_cw; c5.cb[0] = sa_q_cb; c5.mode[0] = 0;
    c5.in[1] = preK;   c5.out[1] = KT;   c5.cw[1] = sa_k_cw; c5.cb[1] = sa_k_cb; c5.mode[1] = 0;
    c5.in[2] = preVsa; c5.out[2] = VNsa; c5.cw[2] = sa_v_cw; c5.cb[2] = sa_v_cb; c5.mode[2] = 1;
    c5.in[3] = preKca; c5.out[3] = KTca; c5.cw[3] = ca_k_cw; c5.cb[3] = ca_k_cb; c5.mode[3] = 0;
    c5.in[4] = preVca; c5.out[4] = VNca; c5.cw[4] = ca_v_cw; c5.cb[4] = ca_v_cb; c5.mode[4] = 1;
    conv5_kernel<<<dim3(64, 5), blk, 0, stream>>>(c5);

    // ---- self attention (fused QK+softmax+PV) ----
    attn_kernel<<<dim3(4, 64), blk, 0, stream>>>(QT, KT, VNsa, qk1o, ATTT, qscale);
    WB8 so;
    so.s[0] = { sa_o_pw, ATTT, saTb, 2 };
    for (int i = 1; i < 8; ++i) so.s[i] = so.s[0];
    wgemmT<128><<<dim3(128), blk, 0, stream>>>(so, 512, 512, 512, 262144, kFW, kFW, 0, 8, 8, 2, 1);

    // ---- cross attention ----
    WB8 cq2;
    cq2.s[0] = { ca_q_pw + 8 * 262144, saTb, PRE16 + 8 * (size_t)kFW, 2 };
    for (int i = 1; i < 8; ++i) cq2.s[i] = cq2.s[0];
    wgemmT<128><<<dim3(128), blk, 0, stream>>>(cq2, 512, 512, 512, 262144, kFW, kFW, 0, 8, 8, 2, 1);
    mixconv_kernel<<<512, blk, 0, stream>>>(PRE16, ca_q_dw, ca_q_cw, ca_q_cb, QTca);

    attn_kernel<<<dim3(4, 64), blk, 0, stream>>>(QTca, KTca, VNca, qk2o, ATTT, qscale);
    WB8 co;
    co.s[0] = { ca_o_pw, ATTT, caTb, 2 };
    for (int i = 1; i < 8; ++i) co.s[i] = co.s[0];
    wgemmT<128><<<dim3(128), blk, 0, stream>>>(co, 512, 512, 512, 262144, kFW, kFW, 0, 8, 8, 2, 1);

    // ---- FFN ----
    WB8 f1;
    f1.s[0] = { ffn1_pw, CAT24, Z0T, 2 };
    for (int i = 1; i < 8; ++i) f1.s[i] = f1.s[0];
    wgemm512<<<dim3(384), blk512, 0, stream>>>(f1, 2048, 512, 512, 1048576, kFW, 524288, 0, 8, 16, 1);
    gelu24_kernel<<<512, blk, 0, stream>>>(Z0T, ffn1_dw);
    WB8 f2;
    f2.s[0] = { ffn2_pw, Z0T, Z2P, 0 };
    for (int i = 1; i < 8; ++i) f2.s[i] = f2.s[0];
    wgemm512<<<dim3(192), blk512, 0, stream>>>(f2, 512, 2048, 1024, 1048576, 524288, kFW, 3145728, 8, 4, 2);
    final_mix_add2<<<512, blk, 0, stream>>>(x, Z2P, ffn2_dw, out);
}